// Round 12
// baseline (186.393 us; speedup 1.0000x reference)
//
#include <hip/hip_runtime.h>

// ---------------------------------------------------------------------------
// PAM module: [prep weights] -> fused conv3x3s2+qkv (bf16 MFMA implicit GEMM)
// -> flash attention v10 (64q/wave nt=4, key-split x8 (x4 fallback), 3-buffer
// single-barrier counted-vmcnt pipeline, K-swizzled LDS, static softmax,
// bf16 partials) -> coalesced merge -> bilinear upsample + residual.
// Shapes: x[8][64][128][128] f32, pooled h=w=64 -> N=4096, d_qk=32, d_v=64.
// ---------------------------------------------------------------------------

typedef __attribute__((ext_vector_type(8))) short bf16x8;   // 8 bf16 (4 VGPRs)
typedef __attribute__((ext_vector_type(4))) float f32x4;

#define DEV static __device__ __forceinline__

DEV unsigned f2bf(float f) {                  // RNE f32 -> bf16 bits
  union { float f; unsigned u; } a; a.f = f;
  return (a.u + 0x7FFFu + ((a.u >> 16) & 1u)) >> 16;
}
DEV float u2f(unsigned u) { union { unsigned u; float f; } a; a.u = u; return a.f; }
DEV unsigned cvtpk(float lo, float hi) {      // v_cvt_pk_bf16_f32 (RNE, 1 instr)
  unsigned r;
  asm("v_cvt_pk_bf16_f32 %0, %1, %2" : "=v"(r) : "v"(lo), "v"(hi));
  return r;
}
DEV bf16x8 mk_bf16x8(unsigned w0, unsigned w1, unsigned w2, unsigned w3) {
  union { unsigned u[4]; bf16x8 v; } x;
  x.u[0] = w0; x.u[1] = w1; x.u[2] = w2; x.u[3] = w3;
  return x.v;
}
DEV void gload_lds16(const void* g, void* l) {
  __builtin_amdgcn_global_load_lds(
      (const __attribute__((address_space(1))) void*)g,
      (__attribute__((address_space(3))) void*)l, 16, 0, 0);
}

// ---------------------------------------------------------------------------
// Kernel 0: weight prep.  Ag[oc][k=tap*64+ic] bf16 (conv A-operand, K=576);
// A2g[row][ic] bf16 (rows 0-31 q_w*log2e, 32-63 k_w, 64-127 v_w); bias2[128].
// ---------------------------------------------------------------------------
__global__ __launch_bounds__(256) void prep_kernel(
    const float* __restrict__ pw, const float* __restrict__ qw,
    const float* __restrict__ kw, const float* __restrict__ vw,
    const float* __restrict__ qb, const float* __restrict__ kb,
    const float* __restrict__ vb,
    unsigned short* __restrict__ Ag, unsigned short* __restrict__ A2g,
    float* __restrict__ bias2) {
  const float LOG2E = 1.4426950408889634f;
  const int i = blockIdx.x * 256 + threadIdx.x;
  if (i < 36864) {
    const int oc = i / 576, k = i - oc * 576;
    const int tap = k >> 6, ic = k & 63;
    Ag[i] = (unsigned short)f2bf(pw[(oc * 64 + ic) * 9 + tap]);
  }
  const int j = i - 36864;
  if (j >= 0 && j < 8192) {
    const int r = j >> 6, c = j & 63;
    if (r < 32)       A2g[j] = (unsigned short)f2bf(qw[r * 64 + c] * LOG2E);
    else if (r < 64)  A2g[j] = (unsigned short)f2bf(kw[(r - 32) * 64 + c]);
    else              A2g[j] = (unsigned short)f2bf(vw[(r - 64) * 64 + c]);
  }
  if (j >= 8192 && j < 8320) {
    const int r = j - 8192;
    bias2[r] = r < 32 ? qb[r] * LOG2E : (r < 64 ? kb[r - 32] : vb[r - 64]);
  }
}

// ---------------------------------------------------------------------------
// Kernel 1: fused conv3x3s2 + qkv, bf16 MFMA 16x16x32 (round-2 verified).
// ---------------------------------------------------------------------------
__global__ __launch_bounds__(256) void convqkv_kernel(
    const float* __restrict__ x, const unsigned short* __restrict__ Ag,
    const float* __restrict__ pool_b, const unsigned short* __restrict__ A2g,
    const float* __restrict__ bias2,
    unsigned short* __restrict__ qT, unsigned short* __restrict__ kT,
    unsigned short* __restrict__ vM) {
  const int b = blockIdx.x >> 6, oy = blockIdx.x & 63;
  const int t = threadIdx.x, w = t >> 6, lane = t & 63;
  const int lr = lane & 15, lg = lane >> 4;
  __shared__ unsigned short sIn[390 * 64];   // 48.75 KB, swizzled bytes
  __shared__ unsigned short sXP[64 * 64];    // 8 KB, swizzled bytes
  char* sInB = (char*)sIn;
  char* sXPB = (char*)sXP;

  bf16x8 af[18];
  {
    const unsigned short* ap = Ag + (w * 16 + lr) * 576 + (lg << 3);
    #pragma unroll
    for (int kc = 0; kc < 18; ++kc)
      af[kc] = *(const bf16x8*)(ap + kc * 32);
  }

  #pragma unroll
  for (int rr = 0; rr < 2; ++rr) {
    const int pos = t + rr * 256;
    if (pos < 390) {
      const int ky = pos / 130, xi = pos - ky * 130;
      const int iy = 2 * oy + ky - 1, ix = xi - 1;
      const bool ok = (iy >= 0) & (iy < 128) & (ix >= 0) & (ix < 128);
      const float* xs = x + ((size_t)(b * 64) * 128 + (ok ? iy : 0)) * 128 +
                        (ok ? ix : 0);
      const int sw = pos & 7;
      #pragma unroll
      for (int o = 0; o < 8; ++o) {
        float f[8];
        #pragma unroll
        for (int jj = 0; jj < 8; ++jj)
          f[jj] = ok ? xs[(size_t)(o * 8 + jj) * 16384] : 0.f;
        bf16x8 v = mk_bf16x8(cvtpk(f[0], f[1]), cvtpk(f[2], f[3]),
                             cvtpk(f[4], f[5]), cvtpk(f[6], f[7]));
        *(bf16x8*)(sInB + pos * 128 + ((o ^ sw) << 4)) = v;
      }
    }
  }
  __syncthreads();

  f32x4 acc[4];
  #pragma unroll
  for (int nt = 0; nt < 4; ++nt) acc[nt] = (f32x4){0.f, 0.f, 0.f, 0.f};
  #pragma unroll
  for (int kc = 0; kc < 18; ++kc) {
    const int tap = kc >> 1, ky = tap / 3, kx = tap - ky * 3;
    const int o = ((kc & 1) << 2) + lg;
    #pragma unroll
    for (int nt = 0; nt < 4; ++nt) {
      const int xi = 2 * (nt * 16 + lr) + kx;
      const int pos = ky * 130 + xi;
      bf16x8 bfr = *(const bf16x8*)(sInB + pos * 128 + ((o ^ (pos & 7)) << 4));
      acc[nt] = __builtin_amdgcn_mfma_f32_16x16x32_bf16(af[kc], bfr, acc[nt],
                                                        0, 0, 0);
    }
  }

  const int ocBase = w * 16 + (lg << 2);
  float pb[4];
  #pragma unroll
  for (int r = 0; r < 4; ++r) pb[r] = pool_b[ocBase + r];
  const int ocOct = ocBase >> 3;
  const int withinB = (ocBase & 7) * 2;
  #pragma unroll
  for (int nt = 0; nt < 4; ++nt) {
    const int pos = nt * 16 + lr;
    const unsigned p01 = cvtpk(acc[nt][0] + pb[0], acc[nt][1] + pb[1]);
    const unsigned p23 = cvtpk(acc[nt][2] + pb[2], acc[nt][3] + pb[3]);
    char* base = sXPB + pos * 128 + ((ocOct ^ (pos & 7)) << 4) + withinB;
    *(unsigned*)(base) = p01;
    *(unsigned*)(base + 4) = p23;
  }
  __syncthreads();

  bf16x8 a2[2][2];
  #pragma unroll
  for (int mt = 0; mt < 2; ++mt)
    #pragma unroll
    for (int kc2 = 0; kc2 < 2; ++kc2)
      a2[mt][kc2] = *(const bf16x8*)(A2g + ((2 * w + mt) * 16 + lr) * 64 +
                                     kc2 * 32 + (lg << 3));
  f32x4 acc2[2][4];
  #pragma unroll
  for (int mt = 0; mt < 2; ++mt)
    #pragma unroll
    for (int nt = 0; nt < 4; ++nt) acc2[mt][nt] = (f32x4){0.f, 0.f, 0.f, 0.f};
  #pragma unroll
  for (int kc2 = 0; kc2 < 2; ++kc2) {
    const int o2 = (kc2 << 2) + lg;
    #pragma unroll
    for (int nt = 0; nt < 4; ++nt) {
      const int pos = nt * 16 + lr;
      bf16x8 bfr = *(const bf16x8*)(sXPB + pos * 128 + ((o2 ^ (pos & 7)) << 4));
      acc2[0][nt] = __builtin_amdgcn_mfma_f32_16x16x32_bf16(a2[0][kc2], bfr,
                                                            acc2[0][nt], 0, 0, 0);
      acc2[1][nt] = __builtin_amdgcn_mfma_f32_16x16x32_bf16(a2[1][kc2], bfr,
                                                            acc2[1][nt], 0, 0, 0);
    }
  }

  const int n0g = oy << 6;
  #pragma unroll
  for (int mt = 0; mt < 2; ++mt) {
    const int rowB = (2 * w + mt) * 16 + (lg << 2);
    float b2[4];
    #pragma unroll
    for (int r = 0; r < 4; ++r) b2[r] = bias2[rowB + r];
    if (rowB < 32) {
      #pragma unroll
      for (int nt = 0; nt < 4; ++nt) {
        const int n = n0g + nt * 16 + lr;
        unsigned* dst = (unsigned*)(qT + (((size_t)(b << 12) + n) << 5) + rowB);
        dst[0] = cvtpk(acc2[mt][nt][0] + b2[0], acc2[mt][nt][1] + b2[1]);
        dst[1] = cvtpk(acc2[mt][nt][2] + b2[2], acc2[mt][nt][3] + b2[3]);
      }
    } else if (rowB < 64) {
      #pragma unroll
      for (int nt = 0; nt < 4; ++nt) {
        const int n = n0g + nt * 16 + lr;
        unsigned* dst = (unsigned*)(kT + (((size_t)(b << 12) + n) << 5) + rowB - 32);
        dst[0] = cvtpk(acc2[mt][nt][0] + b2[0], acc2[mt][nt][1] + b2[1]);
        dst[1] = cvtpk(acc2[mt][nt][2] + b2[2], acc2[mt][nt][3] + b2[3]);
      }
    } else {
      const int cv = rowB - 64;
      #pragma unroll
      for (int nt = 0; nt < 4; ++nt) {
        const int n = n0g + nt * 16 + lr;
        #pragma unroll
        for (int r = 0; r < 4; ++r)
          vM[(((size_t)(b << 6) + cv + r) << 12) + n] =
              (unsigned short)f2bf(acc2[mt][nt][r] + b2[r]);
      }
    }
  }
}

// ---------------------------------------------------------------------------
// Kernel 2: flash attention v10.  Template NSPLIT in {4, 8}.
// Grid 128*NSPLIT = (b = blk&7, u = (blk>>3)&15 [256-q tile], s = blk>>7).
// Block: 4 waves, wave w owns 64 queries (nt=4).  CH=64/NSPLIT chunks of 64
// keys; 3 LDS bufs; STAGE 2 ahead; ONE barrier/chunk: {vmcnt(3); barrier;
// STAGE(cc+2); compute cc} — barrier proves all waves consumed buffer
// (cc-1)%3, which is exactly what STAGE(cc+2) overwrites.
// K staged swizzled: LDS slot sl of key row holds global seg sl^((key>>1)&3)
// -> QK read bank = (key&1)*16 + slot*4 = 2-way only (was 8-way).
// V staged row-major with source octet swizzle (unchanged, verified).
// Static softmax P=2^s' (log2e folded into q).  PV B-frags via round-2-
// verified __shfl(s0/s1)+hi-select.  Partials -> bf16 Pb[s], L f32.
// ---------------------------------------------------------------------------
template <int NSPLIT>
__global__ __launch_bounds__(256, 4) void attn_kernel(
    const unsigned short* __restrict__ qT, const unsigned short* __restrict__ kT,
    const unsigned short* __restrict__ vM,
    unsigned short* __restrict__ Pb, float* __restrict__ Lbuf) {
  constexpr int CH = 64 / NSPLIT;       // chunks per split
  __shared__ char lds[36864];           // 3 bufs x (K 4KB | V 8KB)
  const int t = threadIdx.x, w = t >> 6, lane = t & 63;
  const int lr = lane & 15, lg = lane >> 4;
  const int b = blockIdx.x & 7;
  const int u = (blockIdx.x >> 3) & 15;
  const int s = blockIdx.x >> 7;        // key split
  const int n0 = (u << 8) + (w << 6);   // wave's 64 queries
  const int kb0 = s * (CH << 6);

  bf16x8 bq[4];
  #pragma unroll
  for (int nt = 0; nt < 4; ++nt)
    bq[nt] = *(const bf16x8*)(
        qT + (((size_t)(b << 12) + n0 + nt * 16 + lr) << 5) + (lg << 3));

  const unsigned short* ksrc = kT + ((size_t)b << 17);    // [key][32]
  const unsigned short* vsrcb = vM + ((size_t)b << 18);   // [c][4096]

  f32x4 acc[4][4];
  #pragma unroll
  for (int nt = 0; nt < 4; ++nt)
    #pragma unroll
    for (int ct = 0; ct < 4; ++ct) acc[nt][ct] = (f32x4){0.f, 0.f, 0.f, 0.f};
  float l_run[4] = {0.f, 0.f, 0.f, 0.f};

  const int s0 = lr + ((lane & 16) << 1);   // round-2-verified shuffle map
  const int s1 = s0 + 16;
  const bool hi = (lane & 32) != 0;
  const int vsw = (lane & 7) ^ ((lane >> 3) & 7);   // V source octet swizzle
  // K staging: lane covers key klocal = w*16 + (lane>>2), LDS slot lane&3.
  const int klocal = (w << 4) + (lane >> 2);
  const int kseg = (lane & 3) ^ ((klocal >> 1) & 3); // source seg for slot

  #define STAGE(ci_) {                                                         \
    const int kb_ = kb0 + (((ci_) & (CH - 1)) << 6);                           \
    char* sb_ = lds + ((ci_) % 3) * 12288;                                     \
    gload_lds16((const void*)(ksrc + (((size_t)(kb_ + klocal)) << 5) +         \
                  (kseg << 3)),                                                \
                sb_ + (w << 10));                                              \
    gload_lds16((const void*)(vsrcb +                                          \
                  (((size_t)((w << 4) + (lane >> 3))) << 12) + kb_ +           \
                  (vsw << 3)),                                                 \
                sb_ + 4096 + (w << 11));                                       \
    gload_lds16((const void*)(vsrcb +                                          \
                  (((size_t)((w << 4) + 8 + (lane >> 3))) << 12) + kb_ +       \
                  (vsw << 3)),                                                 \
                sb_ + 4096 + (w << 11) + 1024);                                \
  }

  STAGE(0);
  STAGE(1);

  for (int cc = 0; cc < CH; ++cc) {
    asm volatile("s_waitcnt vmcnt(3)" ::: "memory");   // own chunk-cc loads in
    __builtin_amdgcn_s_barrier();        // all waves have cc; all done w/ cc-1
    __builtin_amdgcn_sched_barrier(0);
    STAGE(cc + 2);                       // overwrites buffer (cc-1)%3: safe
    char* base = lds + (cc % 3) * 12288;

    // ---- QK^T: ka = K[16j+lr][d 8lg..+7] at swizzled slot
    f32x4 st[4][4];
    const f32x4 z4 = {0.f, 0.f, 0.f, 0.f};
    __builtin_amdgcn_s_setprio(1);
    #pragma unroll
    for (int j = 0; j < 4; ++j) {
      const int key = 16 * j + lr;
      const bf16x8 ka = *(const bf16x8*)(
          base + (key << 6) + ((lg ^ ((key >> 1) & 3)) << 4));
      #pragma unroll
      for (int nt = 0; nt < 4; ++nt)
        st[nt][j] = __builtin_amdgcn_mfma_f32_16x16x32_bf16(ka, bq[nt], z4,
                                                            0, 0, 0);
    }
    __builtin_amdgcn_s_setprio(0);

    // ---- static softmax numerator: P = 2^s
    unsigned pw_[4][4][2];
    #pragma unroll
    for (int nt = 0; nt < 4; ++nt) {
      float ps0 = 0.f, ps1 = 0.f;
      #pragma unroll
      for (int j = 0; j < 4; ++j) {
        const float p0 = __builtin_amdgcn_exp2f(st[nt][j][0]);
        const float p1 = __builtin_amdgcn_exp2f(st[nt][j][1]);
        const float p2 = __builtin_amdgcn_exp2f(st[nt][j][2]);
        const float p3 = __builtin_amdgcn_exp2f(st[nt][j][3]);
        ps0 += p0 + p1;
        ps1 += p2 + p3;
        pw_[nt][j][0] = cvtpk(p0, p1);
        pw_[nt][j][1] = cvtpk(p2, p3);
      }
      l_run[nt] += ps0 + ps1;
    }

    // ---- PV: B-frags via shuffles; A-frags V[c][keys 8o..+7] (swizzled)
    #pragma unroll
    for (int h = 0; h < 2; ++h) {
      bf16x8 pbv[4];
      #pragma unroll
      for (int nt = 0; nt < 4; ++nt) {
        const int f0 = 2 * h, f1 = 2 * h + 1;
        const unsigned a0 = __shfl((int)pw_[nt][f0][0], s0, 64);
        const unsigned a1 = __shfl((int)pw_[nt][f0][1], s0, 64);
        const unsigned a2 = __shfl((int)pw_[nt][f0][0], s1, 64);
        const unsigned a3 = __shfl((int)pw_[nt][f0][1], s1, 64);
        const unsigned c0 = __shfl((int)pw_[nt][f1][0], s0, 64);
        const unsigned c1 = __shfl((int)pw_[nt][f1][1], s0, 64);
        const unsigned c2 = __shfl((int)pw_[nt][f1][0], s1, 64);
        const unsigned c3 = __shfl((int)pw_[nt][f1][1], s1, 64);
        pbv[nt] = hi ? mk_bf16x8(c0, c1, c2, c3) : mk_bf16x8(a0, a1, a2, a3);
      }
      __builtin_amdgcn_s_setprio(1);
      #pragma unroll
      for (int ct = 0; ct < 4; ++ct) {
        const int c = (ct << 4) + lr;
        const int o = (h << 2) + lg;
        const bf16x8 va = *(const bf16x8*)(
            base + 4096 + (c << 7) + ((o ^ (lr & 7)) << 4));
        #pragma unroll
        for (int nt = 0; nt < 4; ++nt)
          acc[nt][ct] = __builtin_amdgcn_mfma_f32_16x16x32_bf16(va, pbv[nt],
                                                                acc[nt][ct],
                                                                0, 0, 0);
      }
      __builtin_amdgcn_s_setprio(0);
    }
  }

  #pragma unroll
  for (int nt = 0; nt < 4; ++nt) {
    l_run[nt] += __shfl_xor(l_run[nt], 16, 64);
    l_run[nt] += __shfl_xor(l_run[nt], 32, 64);
  }

  unsigned short* dst = Pb + ((size_t)s << 21);
  #pragma unroll
  for (int nt = 0; nt < 4; ++nt) {
    const int q = n0 + nt * 16 + lr;
    #pragma unroll
    for (int ct = 0; ct < 4; ++ct)
      #pragma unroll
      for (int r = 0; r < 4; ++r) {
        const int c = (ct << 4) + (lg << 2) + r;
        dst[((size_t)((b << 6) + c) << 12) + q] =
            (unsigned short)f2bf(acc[nt][ct][r]);
      }
  }
  if (lane < 16) {
    #pragma unroll
    for (int nt = 0; nt < 4; ++nt)
      Lbuf[((size_t)(s * 8 + b) << 12) + n0 + nt * 16 + lane] = l_run[nt];
  }
  #undef STAGE
}

// ---------------------------------------------------------------------------
// Kernel 2b: coalesced split merge: attnP = gamma * sum_s Pb[s] / sum_s L[s].
// Thread: 8 contiguous n (uint4 bf16x8 load per split).  262144 thr.
// ---------------------------------------------------------------------------
template <int NSPLIT>
__global__ __launch_bounds__(256) void merge_kernel(
    const unsigned short* __restrict__ Pb, const float* __restrict__ Lbuf,
    const float* __restrict__ gamma_p, float* __restrict__ attnP) {
  const int idx = blockIdx.x * 256 + threadIdx.x;
  const int n0 = (idx & 511) << 3;
  const int c = (idx >> 9) & 63;
  const int b = idx >> 15;
  const size_t base = ((size_t)((b << 6) + c) << 12) + n0;

  float num[8] = {0.f, 0.f, 0.f, 0.f, 0.f, 0.f, 0.f, 0.f};
  #pragma unroll
  for (int s = 0; s < NSPLIT; ++s) {
    const uint4 v = *(const uint4*)(Pb + ((size_t)s << 21) + base);
    num[0] += u2f(v.x << 16); num[1] += u2f(v.x & 0xffff0000u);
    num[2] += u2f(v.y << 16); num[3] += u2f(v.y & 0xffff0000u);
    num[4] += u2f(v.z << 16); num[5] += u2f(v.z & 0xffff0000u);
    num[6] += u2f(v.w << 16); num[7] += u2f(v.w & 0xffff0000u);
  }
  float den[8] = {0.f, 0.f, 0.f, 0.f, 0.f, 0.f, 0.f, 0.f};
  #pragma unroll
  for (int s = 0; s < NSPLIT; ++s) {
    const float* lp = Lbuf + (((size_t)(s * 8 + b)) << 12) + n0;
    const f32x4 l0 = *(const f32x4*)lp;
    const f32x4 l1 = *(const f32x4*)(lp + 4);
    #pragma unroll
    for (int j = 0; j < 4; ++j) { den[j] += l0[j]; den[4 + j] += l1[j]; }
  }
  const float g = gamma_p[0];
  f32x4 o0, o1;
  #pragma unroll
  for (int j = 0; j < 4; ++j) {
    o0[j] = g * num[j] / den[j];
    o1[j] = g * num[4 + j] / den[4 + j];
  }
  *(f32x4*)(attnP + base) = o0;
  *(f32x4*)(attnP + base + 4) = o1;
}

// ---------------------------------------------------------------------------
// Kernel 3: bilinear upsample 64->128 (align_corners=True) + residual add.
// ---------------------------------------------------------------------------
__global__ __launch_bounds__(256) void upsample_residual_kernel(
    const float* __restrict__ attn_out, const float* __restrict__ x,
    float* __restrict__ out) {
  const int idx = blockIdx.x * 256 + threadIdx.x;   // 2^21 total
  const int X0 = (idx & 31) << 2;
  int rem = idx >> 5;
  const int Y = rem & 127; rem >>= 7;
  const int c = rem & 63;
  const int b = rem >> 6;

  const float sr = 63.0f / 127.0f;
  float fy = Y * sr;
  int iy = (int)fy; if (iy > 62) iy = 62;
  const float ty = fy - (float)iy;
  const float* ap = attn_out + (((size_t)(b * 64 + c)) << 12);
  const float* r0 = ap + iy * 64;
  const float* r1 = r0 + 64;

  float tmp[4];
  #pragma unroll
  for (int k = 0; k < 4; ++k) {
    const int X = X0 + k;
    float fx = X * sr;
    int ix = (int)fx; if (ix > 62) ix = 62;
    const float tx = fx - (float)ix;
    float v0 = r0[ix] + tx * (r0[ix + 1] - r0[ix]);
    float v1 = r1[ix] + tx * (r1[ix + 1] - r1[ix]);
    tmp[k] = v0 + ty * (v1 - v0);
  }
  const size_t o = (((size_t)((b * 64 + c) * 128 + Y)) << 7) + X0;
  f32x4 xv = *reinterpret_cast<const f32x4*>(x + o);
  f32x4 ov = {tmp[0] + xv[0], tmp[1] + xv[1], tmp[2] + xv[2], tmp[3] + xv[3]};
  *reinterpret_cast<f32x4*>(out + o) = ov;
}

// ---------------------------------------------------------------------------
extern "C" void kernel_launch(void* const* d_in, const int* in_sizes, int n_in,
                              void* d_out, int out_size, void* d_ws, size_t ws_size,
                              hipStream_t stream) {
  const float* x      = (const float*)d_in[0];
  const float* pool_w = (const float*)d_in[1];
  const float* pool_b = (const float*)d_in[2];
  const float* q_w    = (const float*)d_in[3];
  const float* q_b    = (const float*)d_in[4];
  const float* k_w    = (const float*)d_in[5];
  const float* k_b    = (const float*)d_in[6];
  const float* v_w    = (const float*)d_in[7];
  const float* v_b    = (const float*)d_in[8];
  const float* gamma  = (const float*)d_in[9];
  float* out = (float*)d_out;

  char* ws = (char*)d_ws;
  unsigned short* Ag   = (unsigned short*)(ws);             // 73,728 B
  unsigned short* A2g  = (unsigned short*)(ws + 81920);     // 16,384 B
  float* bias2         = (float*)(ws + 98304);              // 512 B
  unsigned short* qT   = (unsigned short*)(ws + 1048576);   // 2 MiB
  unsigned short* kT   = (unsigned short*)(ws + 3145728);   // 2 MiB
  unsigned short* vM   = (unsigned short*)(ws + 5242880);   // 4 MiB
  unsigned short* Pb   = (unsigned short*)(ws + 9437184);   // NSPLIT x 4 MiB
  // attnP f32 (8 MiB) overlays qT/kT/vM — all dead after attn_kernel.
  float* attnP         = (float*)(ws + 1048576);

  prep_kernel<<<177, 256, 0, stream>>>(pool_w, q_w, k_w, v_w, q_b, k_b, v_b,
                                       Ag, A2g, bias2);
  convqkv_kernel<<<512, 256, 0, stream>>>(x, Ag, pool_b, A2g, bias2, qT, kT, vM);

  // 8-split needs 9437184 + 8*4194304 + 8*131072 = 44,040,192 B of ws.
  if (ws_size >= 44040192u) {
    float* Lbuf = (float*)(ws + 9437184 + 8 * 4194304);
    attn_kernel<8><<<1024, 256, 0, stream>>>(qT, kT, vM, Pb, Lbuf);
    merge_kernel<8><<<1024, 256, 0, stream>>>(Pb, Lbuf, gamma, attnP);
  } else {
    float* Lbuf = (float*)(ws + 9437184 + 4 * 4194304);
    attn_kernel<4><<<512, 256, 0, stream>>>(qT, kT, vM, Pb, Lbuf);
    merge_kernel<4><<<1024, 256, 0, stream>>>(Pb, Lbuf, gamma, attnP);
  }
  upsample_residual_kernel<<<8192, 256, 0, stream>>>(attnP, x, out);
}

// Round 13
// 100.901 us; speedup vs baseline: 1.8473x; 1.8473x over previous
//
#include <hip/hip_runtime.h>

// ---------------------------------------------------------------------------
// PAM module: [prep weights] -> fused conv3x3s2+qkv (bf16 MFMA implicit GEMM)
// -> flash attention v10b (64q/wave nt=4, key-split x8 (x4 fallback),
// 3-buffer single-barrier counted-vmcnt pipeline, K-swizzled LDS, static
// softmax, bf16 partials) -> coalesced merge -> bilinear upsample + residual.
// v10 -> v10b: launch_bounds (256,4) -> (256,2).  (256,4) capped VGPR at 64
// and spilled acc/st to scratch: 273MB FETCH + 362MB WRITE per dispatch.
// Shapes: x[8][64][128][128] f32, pooled h=w=64 -> N=4096, d_qk=32, d_v=64.
// ---------------------------------------------------------------------------

typedef __attribute__((ext_vector_type(8))) short bf16x8;   // 8 bf16 (4 VGPRs)
typedef __attribute__((ext_vector_type(4))) float f32x4;

#define DEV static __device__ __forceinline__

DEV unsigned f2bf(float f) {                  // RNE f32 -> bf16 bits
  union { float f; unsigned u; } a; a.f = f;
  return (a.u + 0x7FFFu + ((a.u >> 16) & 1u)) >> 16;
}
DEV float u2f(unsigned u) { union { unsigned u; float f; } a; a.u = u; return a.f; }
DEV unsigned cvtpk(float lo, float hi) {      // v_cvt_pk_bf16_f32 (RNE, 1 instr)
  unsigned r;
  asm("v_cvt_pk_bf16_f32 %0, %1, %2" : "=v"(r) : "v"(lo), "v"(hi));
  return r;
}
DEV bf16x8 mk_bf16x8(unsigned w0, unsigned w1, unsigned w2, unsigned w3) {
  union { unsigned u[4]; bf16x8 v; } x;
  x.u[0] = w0; x.u[1] = w1; x.u[2] = w2; x.u[3] = w3;
  return x.v;
}
DEV void gload_lds16(const void* g, void* l) {
  __builtin_amdgcn_global_load_lds(
      (const __attribute__((address_space(1))) void*)g,
      (__attribute__((address_space(3))) void*)l, 16, 0, 0);
}

// ---------------------------------------------------------------------------
// Kernel 0: weight prep.  Ag[oc][k=tap*64+ic] bf16 (conv A-operand, K=576);
// A2g[row][ic] bf16 (rows 0-31 q_w*log2e, 32-63 k_w, 64-127 v_w); bias2[128].
// ---------------------------------------------------------------------------
__global__ __launch_bounds__(256) void prep_kernel(
    const float* __restrict__ pw, const float* __restrict__ qw,
    const float* __restrict__ kw, const float* __restrict__ vw,
    const float* __restrict__ qb, const float* __restrict__ kb,
    const float* __restrict__ vb,
    unsigned short* __restrict__ Ag, unsigned short* __restrict__ A2g,
    float* __restrict__ bias2) {
  const float LOG2E = 1.4426950408889634f;
  const int i = blockIdx.x * 256 + threadIdx.x;
  if (i < 36864) {
    const int oc = i / 576, k = i - oc * 576;
    const int tap = k >> 6, ic = k & 63;
    Ag[i] = (unsigned short)f2bf(pw[(oc * 64 + ic) * 9 + tap]);
  }
  const int j = i - 36864;
  if (j >= 0 && j < 8192) {
    const int r = j >> 6, c = j & 63;
    if (r < 32)       A2g[j] = (unsigned short)f2bf(qw[r * 64 + c] * LOG2E);
    else if (r < 64)  A2g[j] = (unsigned short)f2bf(kw[(r - 32) * 64 + c]);
    else              A2g[j] = (unsigned short)f2bf(vw[(r - 64) * 64 + c]);
  }
  if (j >= 8192 && j < 8320) {
    const int r = j - 8192;
    bias2[r] = r < 32 ? qb[r] * LOG2E : (r < 64 ? kb[r - 32] : vb[r - 64]);
  }
}

// ---------------------------------------------------------------------------
// Kernel 1: fused conv3x3s2 + qkv, bf16 MFMA 16x16x32 (round-2 verified).
// ---------------------------------------------------------------------------
__global__ __launch_bounds__(256) void convqkv_kernel(
    const float* __restrict__ x, const unsigned short* __restrict__ Ag,
    const float* __restrict__ pool_b, const unsigned short* __restrict__ A2g,
    const float* __restrict__ bias2,
    unsigned short* __restrict__ qT, unsigned short* __restrict__ kT,
    unsigned short* __restrict__ vM) {
  const int b = blockIdx.x >> 6, oy = blockIdx.x & 63;
  const int t = threadIdx.x, w = t >> 6, lane = t & 63;
  const int lr = lane & 15, lg = lane >> 4;
  __shared__ unsigned short sIn[390 * 64];   // 48.75 KB, swizzled bytes
  __shared__ unsigned short sXP[64 * 64];    // 8 KB, swizzled bytes
  char* sInB = (char*)sIn;
  char* sXPB = (char*)sXP;

  bf16x8 af[18];
  {
    const unsigned short* ap = Ag + (w * 16 + lr) * 576 + (lg << 3);
    #pragma unroll
    for (int kc = 0; kc < 18; ++kc)
      af[kc] = *(const bf16x8*)(ap + kc * 32);
  }

  #pragma unroll
  for (int rr = 0; rr < 2; ++rr) {
    const int pos = t + rr * 256;
    if (pos < 390) {
      const int ky = pos / 130, xi = pos - ky * 130;
      const int iy = 2 * oy + ky - 1, ix = xi - 1;
      const bool ok = (iy >= 0) & (iy < 128) & (ix >= 0) & (ix < 128);
      const float* xs = x + ((size_t)(b * 64) * 128 + (ok ? iy : 0)) * 128 +
                        (ok ? ix : 0);
      const int sw = pos & 7;
      #pragma unroll
      for (int o = 0; o < 8; ++o) {
        float f[8];
        #pragma unroll
        for (int jj = 0; jj < 8; ++jj)
          f[jj] = ok ? xs[(size_t)(o * 8 + jj) * 16384] : 0.f;
        bf16x8 v = mk_bf16x8(cvtpk(f[0], f[1]), cvtpk(f[2], f[3]),
                             cvtpk(f[4], f[5]), cvtpk(f[6], f[7]));
        *(bf16x8*)(sInB + pos * 128 + ((o ^ sw) << 4)) = v;
      }
    }
  }
  __syncthreads();

  f32x4 acc[4];
  #pragma unroll
  for (int nt = 0; nt < 4; ++nt) acc[nt] = (f32x4){0.f, 0.f, 0.f, 0.f};
  #pragma unroll
  for (int kc = 0; kc < 18; ++kc) {
    const int tap = kc >> 1, ky = tap / 3, kx = tap - ky * 3;
    const int o = ((kc & 1) << 2) + lg;
    #pragma unroll
    for (int nt = 0; nt < 4; ++nt) {
      const int xi = 2 * (nt * 16 + lr) + kx;
      const int pos = ky * 130 + xi;
      bf16x8 bfr = *(const bf16x8*)(sInB + pos * 128 + ((o ^ (pos & 7)) << 4));
      acc[nt] = __builtin_amdgcn_mfma_f32_16x16x32_bf16(af[kc], bfr, acc[nt],
                                                        0, 0, 0);
    }
  }

  const int ocBase = w * 16 + (lg << 2);
  float pb[4];
  #pragma unroll
  for (int r = 0; r < 4; ++r) pb[r] = pool_b[ocBase + r];
  const int ocOct = ocBase >> 3;
  const int withinB = (ocBase & 7) * 2;
  #pragma unroll
  for (int nt = 0; nt < 4; ++nt) {
    const int pos = nt * 16 + lr;
    const unsigned p01 = cvtpk(acc[nt][0] + pb[0], acc[nt][1] + pb[1]);
    const unsigned p23 = cvtpk(acc[nt][2] + pb[2], acc[nt][3] + pb[3]);
    char* base = sXPB + pos * 128 + ((ocOct ^ (pos & 7)) << 4) + withinB;
    *(unsigned*)(base) = p01;
    *(unsigned*)(base + 4) = p23;
  }
  __syncthreads();

  bf16x8 a2[2][2];
  #pragma unroll
  for (int mt = 0; mt < 2; ++mt)
    #pragma unroll
    for (int kc2 = 0; kc2 < 2; ++kc2)
      a2[mt][kc2] = *(const bf16x8*)(A2g + ((2 * w + mt) * 16 + lr) * 64 +
                                     kc2 * 32 + (lg << 3));
  f32x4 acc2[2][4];
  #pragma unroll
  for (int mt = 0; mt < 2; ++mt)
    #pragma unroll
    for (int nt = 0; nt < 4; ++nt) acc2[mt][nt] = (f32x4){0.f, 0.f, 0.f, 0.f};
  #pragma unroll
  for (int kc2 = 0; kc2 < 2; ++kc2) {
    const int o2 = (kc2 << 2) + lg;
    #pragma unroll
    for (int nt = 0; nt < 4; ++nt) {
      const int pos = nt * 16 + lr;
      bf16x8 bfr = *(const bf16x8*)(sXPB + pos * 128 + ((o2 ^ (pos & 7)) << 4));
      acc2[0][nt] = __builtin_amdgcn_mfma_f32_16x16x32_bf16(a2[0][kc2], bfr,
                                                            acc2[0][nt], 0, 0, 0);
      acc2[1][nt] = __builtin_amdgcn_mfma_f32_16x16x32_bf16(a2[1][kc2], bfr,
                                                            acc2[1][nt], 0, 0, 0);
    }
  }

  const int n0g = oy << 6;
  #pragma unroll
  for (int mt = 0; mt < 2; ++mt) {
    const int rowB = (2 * w + mt) * 16 + (lg << 2);
    float b2[4];
    #pragma unroll
    for (int r = 0; r < 4; ++r) b2[r] = bias2[rowB + r];
    if (rowB < 32) {
      #pragma unroll
      for (int nt = 0; nt < 4; ++nt) {
        const int n = n0g + nt * 16 + lr;
        unsigned* dst = (unsigned*)(qT + (((size_t)(b << 12) + n) << 5) + rowB);
        dst[0] = cvtpk(acc2[mt][nt][0] + b2[0], acc2[mt][nt][1] + b2[1]);
        dst[1] = cvtpk(acc2[mt][nt][2] + b2[2], acc2[mt][nt][3] + b2[3]);
      }
    } else if (rowB < 64) {
      #pragma unroll
      for (int nt = 0; nt < 4; ++nt) {
        const int n = n0g + nt * 16 + lr;
        unsigned* dst = (unsigned*)(kT + (((size_t)(b << 12) + n) << 5) + rowB - 32);
        dst[0] = cvtpk(acc2[mt][nt][0] + b2[0], acc2[mt][nt][1] + b2[1]);
        dst[1] = cvtpk(acc2[mt][nt][2] + b2[2], acc2[mt][nt][3] + b2[3]);
      }
    } else {
      const int cv = rowB - 64;
      #pragma unroll
      for (int nt = 0; nt < 4; ++nt) {
        const int n = n0g + nt * 16 + lr;
        #pragma unroll
        for (int r = 0; r < 4; ++r)
          vM[(((size_t)(b << 6) + cv + r) << 12) + n] =
              (unsigned short)f2bf(acc2[mt][nt][r] + b2[r]);
      }
    }
  }
}

// ---------------------------------------------------------------------------
// Kernel 2: flash attention v10b.  Template NSPLIT in {4, 8}.
// Grid 128*NSPLIT = (b = blk&7, u = (blk>>3)&15 [256-q tile], s = blk>>7).
// Block: 4 waves, wave w owns 64 queries (nt=4).  CH=64/NSPLIT chunks of 64
// keys; 3 LDS bufs; STAGE 2 ahead; ONE barrier/chunk: {vmcnt(3); barrier;
// STAGE(cc+2); compute cc} — barrier proves all waves consumed buffer
// (cc-1)%3, which is exactly what STAGE(cc+2) overwrites.
// K staged swizzled: LDS slot sl of key row holds global seg sl^((key>>1)&3)
// -> QK read bank = (key&1)*16 + slot*4 = 2-way only (was 8-way).
// V staged row-major with source octet swizzle (unchanged, verified).
// Static softmax P=2^s' (log2e folded into q).  PV B-frags via round-2-
// verified __shfl(s0/s1)+hi-select.  Partials -> bf16 Pb[s], L f32.
// launch_bounds (256,2): kernel needs ~96 VGPR; (256,4) caps at 64 -> spill.
// ---------------------------------------------------------------------------
template <int NSPLIT>
__global__ __launch_bounds__(256, 2) void attn_kernel(
    const unsigned short* __restrict__ qT, const unsigned short* __restrict__ kT,
    const unsigned short* __restrict__ vM,
    unsigned short* __restrict__ Pb, float* __restrict__ Lbuf) {
  constexpr int CH = 64 / NSPLIT;       // chunks per split
  __shared__ char lds[36864];           // 3 bufs x (K 4KB | V 8KB)
  const int t = threadIdx.x, w = t >> 6, lane = t & 63;
  const int lr = lane & 15, lg = lane >> 4;
  const int b = blockIdx.x & 7;
  const int u = (blockIdx.x >> 3) & 15;
  const int s = blockIdx.x >> 7;        // key split
  const int n0 = (u << 8) + (w << 6);   // wave's 64 queries
  const int kb0 = s * (CH << 6);

  bf16x8 bq[4];
  #pragma unroll
  for (int nt = 0; nt < 4; ++nt)
    bq[nt] = *(const bf16x8*)(
        qT + (((size_t)(b << 12) + n0 + nt * 16 + lr) << 5) + (lg << 3));

  const unsigned short* ksrc = kT + ((size_t)b << 17);    // [key][32]
  const unsigned short* vsrcb = vM + ((size_t)b << 18);   // [c][4096]

  f32x4 acc[4][4];
  #pragma unroll
  for (int nt = 0; nt < 4; ++nt)
    #pragma unroll
    for (int ct = 0; ct < 4; ++ct) acc[nt][ct] = (f32x4){0.f, 0.f, 0.f, 0.f};
  float l_run[4] = {0.f, 0.f, 0.f, 0.f};

  const int s0 = lr + ((lane & 16) << 1);   // round-2-verified shuffle map
  const int s1 = s0 + 16;
  const bool hi = (lane & 32) != 0;
  const int vsw = (lane & 7) ^ ((lane >> 3) & 7);   // V source octet swizzle
  // K staging: lane covers key klocal = w*16 + (lane>>2), LDS slot lane&3.
  const int klocal = (w << 4) + (lane >> 2);
  const int kseg = (lane & 3) ^ ((klocal >> 1) & 3); // source seg for slot

  #define STAGE(ci_) {                                                         \
    const int kb_ = kb0 + (((ci_) & (CH - 1)) << 6);                           \
    char* sb_ = lds + ((ci_) % 3) * 12288;                                     \
    gload_lds16((const void*)(ksrc + (((size_t)(kb_ + klocal)) << 5) +         \
                  (kseg << 3)),                                                \
                sb_ + (w << 10));                                              \
    gload_lds16((const void*)(vsrcb +                                          \
                  (((size_t)((w << 4) + (lane >> 3))) << 12) + kb_ +           \
                  (vsw << 3)),                                                 \
                sb_ + 4096 + (w << 11));                                       \
    gload_lds16((const void*)(vsrcb +                                          \
                  (((size_t)((w << 4) + 8 + (lane >> 3))) << 12) + kb_ +       \
                  (vsw << 3)),                                                 \
                sb_ + 4096 + (w << 11) + 1024);                                \
  }

  STAGE(0);
  STAGE(1);

  for (int cc = 0; cc < CH; ++cc) {
    asm volatile("s_waitcnt vmcnt(3)" ::: "memory");   // own chunk-cc loads in
    __builtin_amdgcn_s_barrier();        // all waves have cc; all done w/ cc-1
    __builtin_amdgcn_sched_barrier(0);
    STAGE(cc + 2);                       // overwrites buffer (cc-1)%3: safe
    char* base = lds + (cc % 3) * 12288;

    // ---- QK^T: ka = K[16j+lr][d 8lg..+7] at swizzled slot
    f32x4 st[4][4];
    const f32x4 z4 = {0.f, 0.f, 0.f, 0.f};
    __builtin_amdgcn_s_setprio(1);
    #pragma unroll
    for (int j = 0; j < 4; ++j) {
      const int key = 16 * j + lr;
      const bf16x8 ka = *(const bf16x8*)(
          base + (key << 6) + ((lg ^ ((key >> 1) & 3)) << 4));
      #pragma unroll
      for (int nt = 0; nt < 4; ++nt)
        st[nt][j] = __builtin_amdgcn_mfma_f32_16x16x32_bf16(ka, bq[nt], z4,
                                                            0, 0, 0);
    }
    __builtin_amdgcn_s_setprio(0);

    // ---- static softmax numerator: P = 2^s
    unsigned pw_[4][4][2];
    #pragma unroll
    for (int nt = 0; nt < 4; ++nt) {
      float ps0 = 0.f, ps1 = 0.f;
      #pragma unroll
      for (int j = 0; j < 4; ++j) {
        const float p0 = __builtin_amdgcn_exp2f(st[nt][j][0]);
        const float p1 = __builtin_amdgcn_exp2f(st[nt][j][1]);
        const float p2 = __builtin_amdgcn_exp2f(st[nt][j][2]);
        const float p3 = __builtin_amdgcn_exp2f(st[nt][j][3]);
        ps0 += p0 + p1;
        ps1 += p2 + p3;
        pw_[nt][j][0] = cvtpk(p0, p1);
        pw_[nt][j][1] = cvtpk(p2, p3);
      }
      l_run[nt] += ps0 + ps1;
    }

    // ---- PV: B-frags via shuffles; A-frags V[c][keys 8o..+7] (swizzled)
    #pragma unroll
    for (int h = 0; h < 2; ++h) {
      bf16x8 pbv[4];
      #pragma unroll
      for (int nt = 0; nt < 4; ++nt) {
        const int f0 = 2 * h, f1 = 2 * h + 1;
        const unsigned a0 = __shfl((int)pw_[nt][f0][0], s0, 64);
        const unsigned a1 = __shfl((int)pw_[nt][f0][1], s0, 64);
        const unsigned a2 = __shfl((int)pw_[nt][f0][0], s1, 64);
        const unsigned a3 = __shfl((int)pw_[nt][f0][1], s1, 64);
        const unsigned c0 = __shfl((int)pw_[nt][f1][0], s0, 64);
        const unsigned c1 = __shfl((int)pw_[nt][f1][1], s0, 64);
        const unsigned c2 = __shfl((int)pw_[nt][f1][0], s1, 64);
        const unsigned c3 = __shfl((int)pw_[nt][f1][1], s1, 64);
        pbv[nt] = hi ? mk_bf16x8(c0, c1, c2, c3) : mk_bf16x8(a0, a1, a2, a3);
      }
      __builtin_amdgcn_s_setprio(1);
      #pragma unroll
      for (int ct = 0; ct < 4; ++ct) {
        const int c = (ct << 4) + lr;
        const int o = (h << 2) + lg;
        const bf16x8 va = *(const bf16x8*)(
            base + 4096 + (c << 7) + ((o ^ (lr & 7)) << 4));
        #pragma unroll
        for (int nt = 0; nt < 4; ++nt)
          acc[nt][ct] = __builtin_amdgcn_mfma_f32_16x16x32_bf16(va, pbv[nt],
                                                                acc[nt][ct],
                                                                0, 0, 0);
      }
      __builtin_amdgcn_s_setprio(0);
    }
  }

  #pragma unroll
  for (int nt = 0; nt < 4; ++nt) {
    l_run[nt] += __shfl_xor(l_run[nt], 16, 64);
    l_run[nt] += __shfl_xor(l_run[nt], 32, 64);
  }

  unsigned short* dst = Pb + ((size_t)s << 21);
  #pragma unroll
  for (int nt = 0; nt < 4; ++nt) {
    const int q = n0 + nt * 16 + lr;
    #pragma unroll
    for (int ct = 0; ct < 4; ++ct)
      #pragma unroll
      for (int r = 0; r < 4; ++r) {
        const int c = (ct << 4) + (lg << 2) + r;
        dst[((size_t)((b << 6) + c) << 12) + q] =
            (unsigned short)f2bf(acc[nt][ct][r]);
      }
  }
  if (lane < 16) {
    #pragma unroll
    for (int nt = 0; nt < 4; ++nt)
      Lbuf[((size_t)(s * 8 + b) << 12) + n0 + nt * 16 + lane] = l_run[nt];
  }
  #undef STAGE
}

// ---------------------------------------------------------------------------
// Kernel 2b: coalesced split merge: attnP = gamma * sum_s Pb[s] / sum_s L[s].
// Thread: 8 contiguous n (uint4 bf16x8 load per split).  262144 thr.
// ---------------------------------------------------------------------------
template <int NSPLIT>
__global__ __launch_bounds__(256) void merge_kernel(
    const unsigned short* __restrict__ Pb, const float* __restrict__ Lbuf,
    const float* __restrict__ gamma_p, float* __restrict__ attnP) {
  const int idx = blockIdx.x * 256 + threadIdx.x;
  const int n0 = (idx & 511) << 3;
  const int c = (idx >> 9) & 63;
  const int b = idx >> 15;
  const size_t base = ((size_t)((b << 6) + c) << 12) + n0;

  float num[8] = {0.f, 0.f, 0.f, 0.f, 0.f, 0.f, 0.f, 0.f};
  #pragma unroll
  for (int s = 0; s < NSPLIT; ++s) {
    const uint4 v = *(const uint4*)(Pb + ((size_t)s << 21) + base);
    num[0] += u2f(v.x << 16); num[1] += u2f(v.x & 0xffff0000u);
    num[2] += u2f(v.y << 16); num[3] += u2f(v.y & 0xffff0000u);
    num[4] += u2f(v.z << 16); num[5] += u2f(v.z & 0xffff0000u);
    num[6] += u2f(v.w << 16); num[7] += u2f(v.w & 0xffff0000u);
  }
  float den[8] = {0.f, 0.f, 0.f, 0.f, 0.f, 0.f, 0.f, 0.f};
  #pragma unroll
  for (int s = 0; s < NSPLIT; ++s) {
    const float* lp = Lbuf + (((size_t)(s * 8 + b)) << 12) + n0;
    const f32x4 l0 = *(const f32x4*)lp;
    const f32x4 l1 = *(const f32x4*)(lp + 4);
    #pragma unroll
    for (int j = 0; j < 4; ++j) { den[j] += l0[j]; den[4 + j] += l1[j]; }
  }
  const float g = gamma_p[0];
  f32x4 o0, o1;
  #pragma unroll
  for (int j = 0; j < 4; ++j) {
    o0[j] = g * num[j] / den[j];
    o1[j] = g * num[4 + j] / den[4 + j];
  }
  *(f32x4*)(attnP + base) = o0;
  *(f32x4*)(attnP + base + 4) = o1;
}

// ---------------------------------------------------------------------------
// Kernel 3: bilinear upsample 64->128 (align_corners=True) + residual add.
// ---------------------------------------------------------------------------
__global__ __launch_bounds__(256) void upsample_residual_kernel(
    const float* __restrict__ attn_out, const float* __restrict__ x,
    float* __restrict__ out) {
  const int idx = blockIdx.x * 256 + threadIdx.x;   // 2^21 total
  const int X0 = (idx & 31) << 2;
  int rem = idx >> 5;
  const int Y = rem & 127; rem >>= 7;
  const int c = rem & 63;
  const int b = rem >> 6;

  const float sr = 63.0f / 127.0f;
  float fy = Y * sr;
  int iy = (int)fy; if (iy > 62) iy = 62;
  const float ty = fy - (float)iy;
  const float* ap = attn_out + (((size_t)(b * 64 + c)) << 12);
  const float* r0 = ap + iy * 64;
  const float* r1 = r0 + 64;

  float tmp[4];
  #pragma unroll
  for (int k = 0; k < 4; ++k) {
    const int X = X0 + k;
    float fx = X * sr;
    int ix = (int)fx; if (ix > 62) ix = 62;
    const float tx = fx - (float)ix;
    float v0 = r0[ix] + tx * (r0[ix + 1] - r0[ix]);
    float v1 = r1[ix] + tx * (r1[ix + 1] - r1[ix]);
    tmp[k] = v0 + ty * (v1 - v0);
  }
  const size_t o = (((size_t)((b * 64 + c) * 128 + Y)) << 7) + X0;
  f32x4 xv = *reinterpret_cast<const f32x4*>(x + o);
  f32x4 ov = {tmp[0] + xv[0], tmp[1] + xv[1], tmp[2] + xv[2], tmp[3] + xv[3]};
  *reinterpret_cast<f32x4*>(out + o) = ov;
}

// ---------------------------------------------------------------------------
extern "C" void kernel_launch(void* const* d_in, const int* in_sizes, int n_in,
                              void* d_out, int out_size, void* d_ws, size_t ws_size,
                              hipStream_t stream) {
  const float* x      = (const float*)d_in[0];
  const float* pool_w = (const float*)d_in[1];
  const float* pool_b = (const float*)d_in[2];
  const float* q_w    = (const float*)d_in[3];
  const float* q_b    = (const float*)d_in[4];
  const float* k_w    = (const float*)d_in[5];
  const float* k_b    = (const float*)d_in[6];
  const float* v_w    = (const float*)d_in[7];
  const float* v_b    = (const float*)d_in[8];
  const float* gamma  = (const float*)d_in[9];
  float* out = (float*)d_out;

  char* ws = (char*)d_ws;
  unsigned short* Ag   = (unsigned short*)(ws);             // 73,728 B
  unsigned short* A2g  = (unsigned short*)(ws + 81920);     // 16,384 B
  float* bias2         = (float*)(ws + 98304);              // 512 B
  unsigned short* qT   = (unsigned short*)(ws + 1048576);   // 2 MiB
  unsigned short* kT   = (unsigned short*)(ws + 3145728);   // 2 MiB
  unsigned short* vM   = (unsigned short*)(ws + 5242880);   // 4 MiB
  unsigned short* Pb   = (unsigned short*)(ws + 9437184);   // NSPLIT x 4 MiB
  // attnP f32 (8 MiB) overlays qT/kT/vM — all dead after attn_kernel.
  float* attnP         = (float*)(ws + 1048576);

  prep_kernel<<<177, 256, 0, stream>>>(pool_w, q_w, k_w, v_w, q_b, k_b, v_b,
                                       Ag, A2g, bias2);
  convqkv_kernel<<<512, 256, 0, stream>>>(x, Ag, pool_b, A2g, bias2, qT, kT, vM);

  // 8-split needs 9437184 + 8*4194304 + 8*131072 = 44,040,192 B of ws.
  if (ws_size >= 44040192u) {
    float* Lbuf = (float*)(ws + 9437184 + 8 * 4194304);
    attn_kernel<8><<<1024, 256, 0, stream>>>(qT, kT, vM, Pb, Lbuf);
    merge_kernel<8><<<1024, 256, 0, stream>>>(Pb, Lbuf, gamma, attnP);
  } else {
    float* Lbuf = (float*)(ws + 9437184 + 4 * 4194304);
    attn_kernel<4><<<512, 256, 0, stream>>>(qT, kT, vM, Pb, Lbuf);
    merge_kernel<4><<<1024, 256, 0, stream>>>(Pb, Lbuf, gamma, attnP);
  }
  upsample_residual_kernel<<<8192, 256, 0, stream>>>(attnP, x, out);
}

// Round 14
// 90.895 us; speedup vs baseline: 2.0506x; 1.1101x over previous
//
#include <hip/hip_runtime.h>

// ---------------------------------------------------------------------------
// PAM module: [prep weights] -> fused conv3x3s2+qkv (bf16 MFMA implicit GEMM)
// -> flash attention v11 (64q/wave nt=4, key-split x8 (x4 fallback), 2-buffer
// single-barrier pipeline, K-swizzled LDS, LDS P-transpose PV (r6-verified,
// replaces 64 ds_bpermute/chunk), static softmax, bf16 partials)
// -> coalesced merge -> bilinear upsample + residual.
// Shapes: x[8][64][128][128] f32, pooled h=w=64 -> N=4096, d_qk=32, d_v=64.
// ---------------------------------------------------------------------------

typedef __attribute__((ext_vector_type(8))) short bf16x8;   // 8 bf16 (4 VGPRs)
typedef __attribute__((ext_vector_type(4))) float f32x4;

#define DEV static __device__ __forceinline__

DEV unsigned f2bf(float f) {                  // RNE f32 -> bf16 bits
  union { float f; unsigned u; } a; a.f = f;
  return (a.u + 0x7FFFu + ((a.u >> 16) & 1u)) >> 16;
}
DEV float u2f(unsigned u) { union { unsigned u; float f; } a; a.u = u; return a.f; }
DEV unsigned cvtpk(float lo, float hi) {      // v_cvt_pk_bf16_f32 (RNE, 1 instr)
  unsigned r;
  asm("v_cvt_pk_bf16_f32 %0, %1, %2" : "=v"(r) : "v"(lo), "v"(hi));
  return r;
}
DEV bf16x8 mk_bf16x8(unsigned w0, unsigned w1, unsigned w2, unsigned w3) {
  union { unsigned u[4]; bf16x8 v; } x;
  x.u[0] = w0; x.u[1] = w1; x.u[2] = w2; x.u[3] = w3;
  return x.v;
}
DEV void gload_lds16(const void* g, void* l) {
  __builtin_amdgcn_global_load_lds(
      (const __attribute__((address_space(1))) void*)g,
      (__attribute__((address_space(3))) void*)l, 16, 0, 0);
}

// ---------------------------------------------------------------------------
// Kernel 0: weight prep.  Ag[oc][k=tap*64+ic] bf16 (conv A-operand, K=576);
// A2g[row][ic] bf16 (rows 0-31 q_w*log2e, 32-63 k_w, 64-127 v_w); bias2[128].
// ---------------------------------------------------------------------------
__global__ __launch_bounds__(256) void prep_kernel(
    const float* __restrict__ pw, const float* __restrict__ qw,
    const float* __restrict__ kw, const float* __restrict__ vw,
    const float* __restrict__ qb, const float* __restrict__ kb,
    const float* __restrict__ vb,
    unsigned short* __restrict__ Ag, unsigned short* __restrict__ A2g,
    float* __restrict__ bias2) {
  const float LOG2E = 1.4426950408889634f;
  const int i = blockIdx.x * 256 + threadIdx.x;
  if (i < 36864) {
    const int oc = i / 576, k = i - oc * 576;
    const int tap = k >> 6, ic = k & 63;
    Ag[i] = (unsigned short)f2bf(pw[(oc * 64 + ic) * 9 + tap]);
  }
  const int j = i - 36864;
  if (j >= 0 && j < 8192) {
    const int r = j >> 6, c = j & 63;
    if (r < 32)       A2g[j] = (unsigned short)f2bf(qw[r * 64 + c] * LOG2E);
    else if (r < 64)  A2g[j] = (unsigned short)f2bf(kw[(r - 32) * 64 + c]);
    else              A2g[j] = (unsigned short)f2bf(vw[(r - 64) * 64 + c]);
  }
  if (j >= 8192 && j < 8320) {
    const int r = j - 8192;
    bias2[r] = r < 32 ? qb[r] * LOG2E : (r < 64 ? kb[r - 32] : vb[r - 64]);
  }
}

// ---------------------------------------------------------------------------
// Kernel 1: fused conv3x3s2 + qkv, bf16 MFMA 16x16x32 (round-2 verified).
// ---------------------------------------------------------------------------
__global__ __launch_bounds__(256) void convqkv_kernel(
    const float* __restrict__ x, const unsigned short* __restrict__ Ag,
    const float* __restrict__ pool_b, const unsigned short* __restrict__ A2g,
    const float* __restrict__ bias2,
    unsigned short* __restrict__ qT, unsigned short* __restrict__ kT,
    unsigned short* __restrict__ vM) {
  const int b = blockIdx.x >> 6, oy = blockIdx.x & 63;
  const int t = threadIdx.x, w = t >> 6, lane = t & 63;
  const int lr = lane & 15, lg = lane >> 4;
  __shared__ unsigned short sIn[390 * 64];   // 48.75 KB, swizzled bytes
  __shared__ unsigned short sXP[64 * 64];    // 8 KB, swizzled bytes
  char* sInB = (char*)sIn;
  char* sXPB = (char*)sXP;

  bf16x8 af[18];
  {
    const unsigned short* ap = Ag + (w * 16 + lr) * 576 + (lg << 3);
    #pragma unroll
    for (int kc = 0; kc < 18; ++kc)
      af[kc] = *(const bf16x8*)(ap + kc * 32);
  }

  #pragma unroll
  for (int rr = 0; rr < 2; ++rr) {
    const int pos = t + rr * 256;
    if (pos < 390) {
      const int ky = pos / 130, xi = pos - ky * 130;
      const int iy = 2 * oy + ky - 1, ix = xi - 1;
      const bool ok = (iy >= 0) & (iy < 128) & (ix >= 0) & (ix < 128);
      const float* xs = x + ((size_t)(b * 64) * 128 + (ok ? iy : 0)) * 128 +
                        (ok ? ix : 0);
      const int sw = pos & 7;
      #pragma unroll
      for (int o = 0; o < 8; ++o) {
        float f[8];
        #pragma unroll
        for (int jj = 0; jj < 8; ++jj)
          f[jj] = ok ? xs[(size_t)(o * 8 + jj) * 16384] : 0.f;
        bf16x8 v = mk_bf16x8(cvtpk(f[0], f[1]), cvtpk(f[2], f[3]),
                             cvtpk(f[4], f[5]), cvtpk(f[6], f[7]));
        *(bf16x8*)(sInB + pos * 128 + ((o ^ sw) << 4)) = v;
      }
    }
  }
  __syncthreads();

  f32x4 acc[4];
  #pragma unroll
  for (int nt = 0; nt < 4; ++nt) acc[nt] = (f32x4){0.f, 0.f, 0.f, 0.f};
  #pragma unroll
  for (int kc = 0; kc < 18; ++kc) {
    const int tap = kc >> 1, ky = tap / 3, kx = tap - ky * 3;
    const int o = ((kc & 1) << 2) + lg;
    #pragma unroll
    for (int nt = 0; nt < 4; ++nt) {
      const int xi = 2 * (nt * 16 + lr) + kx;
      const int pos = ky * 130 + xi;
      bf16x8 bfr = *(const bf16x8*)(sInB + pos * 128 + ((o ^ (pos & 7)) << 4));
      acc[nt] = __builtin_amdgcn_mfma_f32_16x16x32_bf16(af[kc], bfr, acc[nt],
                                                        0, 0, 0);
    }
  }

  const int ocBase = w * 16 + (lg << 2);
  float pb[4];
  #pragma unroll
  for (int r = 0; r < 4; ++r) pb[r] = pool_b[ocBase + r];
  const int ocOct = ocBase >> 3;
  const int withinB = (ocBase & 7) * 2;
  #pragma unroll
  for (int nt = 0; nt < 4; ++nt) {
    const int pos = nt * 16 + lr;
    const unsigned p01 = cvtpk(acc[nt][0] + pb[0], acc[nt][1] + pb[1]);
    const unsigned p23 = cvtpk(acc[nt][2] + pb[2], acc[nt][3] + pb[3]);
    char* base = sXPB + pos * 128 + ((ocOct ^ (pos & 7)) << 4) + withinB;
    *(unsigned*)(base) = p01;
    *(unsigned*)(base + 4) = p23;
  }
  __syncthreads();

  bf16x8 a2[2][2];
  #pragma unroll
  for (int mt = 0; mt < 2; ++mt)
    #pragma unroll
    for (int kc2 = 0; kc2 < 2; ++kc2)
      a2[mt][kc2] = *(const bf16x8*)(A2g + ((2 * w + mt) * 16 + lr) * 64 +
                                     kc2 * 32 + (lg << 3));
  f32x4 acc2[2][4];
  #pragma unroll
  for (int mt = 0; mt < 2; ++mt)
    #pragma unroll
    for (int nt = 0; nt < 4; ++nt) acc2[mt][nt] = (f32x4){0.f, 0.f, 0.f, 0.f};
  #pragma unroll
  for (int kc2 = 0; kc2 < 2; ++kc2) {
    const int o2 = (kc2 << 2) + lg;
    #pragma unroll
    for (int nt = 0; nt < 4; ++nt) {
      const int pos = nt * 16 + lr;
      bf16x8 bfr = *(const bf16x8*)(sXPB + pos * 128 + ((o2 ^ (pos & 7)) << 4));
      acc2[0][nt] = __builtin_amdgcn_mfma_f32_16x16x32_bf16(a2[0][kc2], bfr,
                                                            acc2[0][nt], 0, 0, 0);
      acc2[1][nt] = __builtin_amdgcn_mfma_f32_16x16x32_bf16(a2[1][kc2], bfr,
                                                            acc2[1][nt], 0, 0, 0);
    }
  }

  const int n0g = oy << 6;
  #pragma unroll
  for (int mt = 0; mt < 2; ++mt) {
    const int rowB = (2 * w + mt) * 16 + (lg << 2);
    float b2[4];
    #pragma unroll
    for (int r = 0; r < 4; ++r) b2[r] = bias2[rowB + r];
    if (rowB < 32) {
      #pragma unroll
      for (int nt = 0; nt < 4; ++nt) {
        const int n = n0g + nt * 16 + lr;
        unsigned* dst = (unsigned*)(qT + (((size_t)(b << 12) + n) << 5) + rowB);
        dst[0] = cvtpk(acc2[mt][nt][0] + b2[0], acc2[mt][nt][1] + b2[1]);
        dst[1] = cvtpk(acc2[mt][nt][2] + b2[2], acc2[mt][nt][3] + b2[3]);
      }
    } else if (rowB < 64) {
      #pragma unroll
      for (int nt = 0; nt < 4; ++nt) {
        const int n = n0g + nt * 16 + lr;
        unsigned* dst = (unsigned*)(kT + (((size_t)(b << 12) + n) << 5) + rowB - 32);
        dst[0] = cvtpk(acc2[mt][nt][0] + b2[0], acc2[mt][nt][1] + b2[1]);
        dst[1] = cvtpk(acc2[mt][nt][2] + b2[2], acc2[mt][nt][3] + b2[3]);
      }
    } else {
      const int cv = rowB - 64;
      #pragma unroll
      for (int nt = 0; nt < 4; ++nt) {
        const int n = n0g + nt * 16 + lr;
        #pragma unroll
        for (int r = 0; r < 4; ++r)
          vM[(((size_t)(b << 6) + cv + r) << 12) + n] =
              (unsigned short)f2bf(acc2[mt][nt][r] + b2[r]);
      }
    }
  }
}

// ---------------------------------------------------------------------------
// Kernel 2: flash attention v11.  Template NSPLIT in {4, 8}.
// Grid 128*NSPLIT = (b = blk&7, u = (blk>>3)&15 [256-q tile], s = blk>>7).
// Block: 4 waves, wave w owns 64 queries (nt=4).  CH=64/NSPLIT chunks of 64
// keys; 2 LDS staging bufs, prefetch distance 1, ONE barrier/chunk:
// {vmcnt(0) [chunk cc landed]; barrier [all waves' reads of cc-1 drained
// (each wave lgkm-drained before its MFMAs)]; STAGE(cc+1) [overwrites buf
// (cc-1)%2: safe]; compute cc}.
// K staged swizzled (r13-verified): slot sl holds seg sl^((key>>1)&3).
// V staged row-major w/ source octet swizzle (r9-13-verified).
// P redistribution via per-wave LDS transpose (r6-verified addressing,
// stride 144B): 16 ds_write_b64 + 8 ds_read_b128 per chunk replaces
// 64 ds_bpermute.  Static softmax P=2^s' (log2e folded into q).
// Partials -> bf16 Pb[s], L f32.  launch_bounds (256,2): needs ~96 VGPR.
// ---------------------------------------------------------------------------
template <int NSPLIT>
__global__ __launch_bounds__(256, 2) void attn_kernel(
    const unsigned short* __restrict__ qT, const unsigned short* __restrict__ kT,
    const unsigned short* __restrict__ vM,
    unsigned short* __restrict__ Pb, float* __restrict__ Lbuf) {
  constexpr int CH = 64 / NSPLIT;       // chunks per split
  __shared__ char lds[24576];           // 2 bufs x (K 4KB | V 8KB)
  __shared__ char Plds[4][9216];        // per-wave P: 64 rows x 144B
  const int t = threadIdx.x, w = t >> 6, lane = t & 63;
  const int lr = lane & 15, lg = lane >> 4;
  const int b = blockIdx.x & 7;
  const int u = (blockIdx.x >> 3) & 15;
  const int s = blockIdx.x >> 7;        // key split
  const int n0 = (u << 8) + (w << 6);   // wave's 64 queries
  const int kb0 = s * (CH << 6);
  char* Pw = Plds[w];

  bf16x8 bq[4];
  #pragma unroll
  for (int nt = 0; nt < 4; ++nt)
    bq[nt] = *(const bf16x8*)(
        qT + (((size_t)(b << 12) + n0 + nt * 16 + lr) << 5) + (lg << 3));

  const unsigned short* ksrc = kT + ((size_t)b << 17);    // [key][32]
  const unsigned short* vsrcb = vM + ((size_t)b << 18);   // [c][4096]

  f32x4 acc[4][4];
  #pragma unroll
  for (int nt = 0; nt < 4; ++nt)
    #pragma unroll
    for (int ct = 0; ct < 4; ++ct) acc[nt][ct] = (f32x4){0.f, 0.f, 0.f, 0.f};
  float l_run[4] = {0.f, 0.f, 0.f, 0.f};

  const int vsw = (lane & 7) ^ ((lane >> 3) & 7);   // V source octet swizzle
  // K staging: lane covers key klocal = w*16 + (lane>>2), LDS slot lane&3.
  const int klocal = (w << 4) + (lane >> 2);
  const int kseg = (lane & 3) ^ ((klocal >> 1) & 3); // source seg for slot

  #define STAGE(ci_) {                                                         \
    const int kb_ = kb0 + (((ci_) & (CH - 1)) << 6);                           \
    char* sb_ = lds + ((ci_) & 1) * 12288;                                     \
    gload_lds16((const void*)(ksrc + (((size_t)(kb_ + klocal)) << 5) +         \
                  (kseg << 3)),                                                \
                sb_ + (w << 10));                                              \
    gload_lds16((const void*)(vsrcb +                                          \
                  (((size_t)((w << 4) + (lane >> 3))) << 12) + kb_ +           \
                  (vsw << 3)),                                                 \
                sb_ + 4096 + (w << 11));                                       \
    gload_lds16((const void*)(vsrcb +                                          \
                  (((size_t)((w << 4) + 8 + (lane >> 3))) << 12) + kb_ +       \
                  (vsw << 3)),                                                 \
                sb_ + 4096 + (w << 11) + 1024);                                \
  }

  STAGE(0);

  for (int cc = 0; cc < CH; ++cc) {
    asm volatile("s_waitcnt vmcnt(0)" ::: "memory");   // chunk cc landed
    __builtin_amdgcn_s_barrier();        // all waves consumed buf (cc-1)&1
    __builtin_amdgcn_sched_barrier(0);
    if (cc + 1 < CH) STAGE(cc + 1);      // overwrites buf (cc-1)&1: safe
    char* base = lds + (cc & 1) * 12288;

    // ---- QK^T: ka = K[16j+lr][d 8lg..+7] at swizzled slot
    f32x4 st[4][4];
    const f32x4 z4 = {0.f, 0.f, 0.f, 0.f};
    __builtin_amdgcn_s_setprio(1);
    #pragma unroll
    for (int j = 0; j < 4; ++j) {
      const int key = 16 * j + lr;
      const bf16x8 ka = *(const bf16x8*)(
          base + (key << 6) + ((lg ^ ((key >> 1) & 3)) << 4));
      #pragma unroll
      for (int nt = 0; nt < 4; ++nt)
        st[nt][j] = __builtin_amdgcn_mfma_f32_16x16x32_bf16(ka, bq[nt], z4,
                                                            0, 0, 0);
    }
    __builtin_amdgcn_s_setprio(0);

    // ---- static softmax numerator P = 2^s; transpose P into LDS
    // (r6-verified): keys 16j+4lg..+3 at row q = nt*16+lr, slot 4j+lg.
    #pragma unroll
    for (int nt = 0; nt < 4; ++nt) {
      float ps0 = 0.f, ps1 = 0.f;
      #pragma unroll
      for (int j = 0; j < 4; ++j) {
        const float p0 = __builtin_amdgcn_exp2f(st[nt][j][0]);
        const float p1 = __builtin_amdgcn_exp2f(st[nt][j][1]);
        const float p2 = __builtin_amdgcn_exp2f(st[nt][j][2]);
        const float p3 = __builtin_amdgcn_exp2f(st[nt][j][3]);
        ps0 += p0 + p1;
        ps1 += p2 + p3;
        *(uint2*)(Pw + (nt * 16 + lr) * 144 + (((j << 2) + lg) << 3)) =
            (uint2){cvtpk(p0, p1), cvtpk(p2, p3)};
      }
      l_run[nt] += ps0 + ps1;
    }

    // ---- PV: B-frag = P[q=nt*16+lr][keys 32h+8lg..+7] one b128 read;
    //      A-frag V[c][keys 8o..+7] (source-swizzled layout).
    #pragma unroll
    for (int h = 0; h < 2; ++h) {
      bf16x8 vr[4];
      #pragma unroll
      for (int ct = 0; ct < 4; ++ct) {
        const int c = (ct << 4) + lr;
        const int o = (h << 2) + lg;
        vr[ct] = *(const bf16x8*)(base + 4096 + (c << 7) +
                                  ((o ^ (lr & 7)) << 4));
      }
      #pragma unroll
      for (int nt = 0; nt < 4; ++nt) {
        const bf16x8 pbf = *(const bf16x8*)(
            Pw + (nt * 16 + lr) * 144 + (((h << 3) + (lg << 1)) << 3));
        __builtin_amdgcn_s_setprio(1);
        #pragma unroll
        for (int ct = 0; ct < 4; ++ct)
          acc[nt][ct] = __builtin_amdgcn_mfma_f32_16x16x32_bf16(vr[ct], pbf,
                                                                acc[nt][ct],
                                                                0, 0, 0);
        __builtin_amdgcn_s_setprio(0);
      }
    }
  }

  #pragma unroll
  for (int nt = 0; nt < 4; ++nt) {
    l_run[nt] += __shfl_xor(l_run[nt], 16, 64);
    l_run[nt] += __shfl_xor(l_run[nt], 32, 64);
  }

  unsigned short* dst = Pb + ((size_t)s << 21);
  #pragma unroll
  for (int nt = 0; nt < 4; ++nt) {
    const int q = n0 + nt * 16 + lr;
    #pragma unroll
    for (int ct = 0; ct < 4; ++ct)
      #pragma unroll
      for (int r = 0; r < 4; ++r) {
        const int c = (ct << 4) + (lg << 2) + r;
        dst[((size_t)((b << 6) + c) << 12) + q] =
            (unsigned short)f2bf(acc[nt][ct][r]);
      }
  }
  if (lane < 16) {
    #pragma unroll
    for (int nt = 0; nt < 4; ++nt)
      Lbuf[((size_t)(s * 8 + b) << 12) + n0 + nt * 16 + lane] = l_run[nt];
  }
  #undef STAGE
}

// ---------------------------------------------------------------------------
// Kernel 2b: coalesced split merge: attnP = gamma * sum_s Pb[s] / sum_s L[s].
// Thread: 8 contiguous n (uint4 bf16x8 load per split).  262144 thr.
// ---------------------------------------------------------------------------
template <int NSPLIT>
__global__ __launch_bounds__(256) void merge_kernel(
    const unsigned short* __restrict__ Pb, const float* __restrict__ Lbuf,
    const float* __restrict__ gamma_p, float* __restrict__ attnP) {
  const int idx = blockIdx.x * 256 + threadIdx.x;
  const int n0 = (idx & 511) << 3;
  const int c = (idx >> 9) & 63;
  const int b = idx >> 15;
  const size_t base = ((size_t)((b << 6) + c) << 12) + n0;

  float num[8] = {0.f, 0.f, 0.f, 0.f, 0.f, 0.f, 0.f, 0.f};
  #pragma unroll
  for (int s = 0; s < NSPLIT; ++s) {
    const uint4 v = *(const uint4*)(Pb + ((size_t)s << 21) + base);
    num[0] += u2f(v.x << 16); num[1] += u2f(v.x & 0xffff0000u);
    num[2] += u2f(v.y << 16); num[3] += u2f(v.y & 0xffff0000u);
    num[4] += u2f(v.z << 16); num[5] += u2f(v.z & 0xffff0000u);
    num[6] += u2f(v.w << 16); num[7] += u2f(v.w & 0xffff0000u);
  }
  float den[8] = {0.f, 0.f, 0.f, 0.f, 0.f, 0.f, 0.f, 0.f};
  #pragma unroll
  for (int s = 0; s < NSPLIT; ++s) {
    const float* lp = Lbuf + (((size_t)(s * 8 + b)) << 12) + n0;
    const f32x4 l0 = *(const f32x4*)lp;
    const f32x4 l1 = *(const f32x4*)(lp + 4);
    #pragma unroll
    for (int j = 0; j < 4; ++j) { den[j] += l0[j]; den[4 + j] += l1[j]; }
  }
  const float g = gamma_p[0];
  f32x4 o0, o1;
  #pragma unroll
  for (int j = 0; j < 4; ++j) {
    o0[j] = g * num[j] / den[j];
    o1[j] = g * num[4 + j] / den[4 + j];
  }
  *(f32x4*)(attnP + base) = o0;
  *(f32x4*)(attnP + base + 4) = o1;
}

// ---------------------------------------------------------------------------
// Kernel 3: bilinear upsample 64->128 (align_corners=True) + residual add.
// ---------------------------------------------------------------------------
__global__ __launch_bounds__(256) void upsample_residual_kernel(
    const float* __restrict__ attn_out, const float* __restrict__ x,
    float* __restrict__ out) {
  const int idx = blockIdx.x * 256 + threadIdx.x;   // 2^21 total
  const int X0 = (idx & 31) << 2;
  int rem = idx >> 5;
  const int Y = rem & 127; rem >>= 7;
  const int c = rem & 63;
  const int b = rem >> 6;

  const float sr = 63.0f / 127.0f;
  float fy = Y * sr;
  int iy = (int)fy; if (iy > 62) iy = 62;
  const float ty = fy - (float)iy;
  const float* ap = attn_out + (((size_t)(b * 64 + c)) << 12);
  const float* r0 = ap + iy * 64;
  const float* r1 = r0 + 64;

  float tmp[4];
  #pragma unroll
  for (int k = 0; k < 4; ++k) {
    const int X = X0 + k;
    float fx = X * sr;
    int ix = (int)fx; if (ix > 62) ix = 62;
    const float tx = fx - (float)ix;
    float v0 = r0[ix] + tx * (r0[ix + 1] - r0[ix]);
    float v1 = r1[ix] + tx * (r1[ix + 1] - r1[ix]);
    tmp[k] = v0 + ty * (v1 - v0);
  }
  const size_t o = (((size_t)((b * 64 + c) * 128 + Y)) << 7) + X0;
  f32x4 xv = *reinterpret_cast<const f32x4*>(x + o);
  f32x4 ov = {tmp[0] + xv[0], tmp[1] + xv[1], tmp[2] + xv[2], tmp[3] + xv[3]};
  *reinterpret_cast<f32x4*>(out + o) = ov;
}

// ---------------------------------------------------------------------------
extern "C" void kernel_launch(void* const* d_in, const int* in_sizes, int n_in,
                              void* d_out, int out_size, void* d_ws, size_t ws_size,
                              hipStream_t stream) {
  const float* x      = (const float*)d_in[0];
  const float* pool_w = (const float*)d_in[1];
  const float* pool_b = (const float*)d_in[2];
  const float* q_w    = (const float*)d_in[3];
  const float* q_b    = (const float*)d_in[4];
  const float* k_w    = (const float*)d_in[5];
  const float* k_b    = (const float*)d_in[6];
  const float* v_w    = (const float*)d_in[7];
  const float* v_b    = (const float*)d_in[8];
  const float* gamma  = (const float*)d_in[9];
  float* out = (float*)d_out;

  char* ws = (char*)d_ws;
  unsigned short* Ag   = (unsigned short*)(ws);             // 73,728 B
  unsigned short* A2g  = (unsigned short*)(ws + 81920);     // 16,384 B
  float* bias2         = (float*)(ws + 98304);              // 512 B
  unsigned short* qT   = (unsigned short*)(ws + 1048576);   // 2 MiB
  unsigned short* kT   = (unsigned short*)(ws + 3145728);   // 2 MiB
  unsigned short* vM   = (unsigned short*)(ws + 5242880);   // 4 MiB
  unsigned short* Pb   = (unsigned short*)(ws + 9437184);   // NSPLIT x 4 MiB
  // attnP f32 (8 MiB) overlays qT/kT/vM — all dead after attn_kernel.
  float* attnP         = (float*)(ws + 1048576);

  prep_kernel<<<177, 256, 0, stream>>>(pool_w, q_w, k_w, v_w, q_b, k_b, v_b,
                                       Ag, A2g, bias2);
  convqkv_kernel<<<512, 256, 0, stream>>>(x, Ag, pool_b, A2g, bias2, qT, kT, vM);

  // 8-split needs 9437184 + 8*4194304 + 8*131072 = 44,040,192 B of ws.
  if (ws_size >= 44040192u) {
    float* Lbuf = (float*)(ws + 9437184 + 8 * 4194304);
    attn_kernel<8><<<1024, 256, 0, stream>>>(qT, kT, vM, Pb, Lbuf);
    merge_kernel<8><<<1024, 256, 0, stream>>>(Pb, Lbuf, gamma, attnP);
  } else {
    float* Lbuf = (float*)(ws + 9437184 + 4 * 4194304);
    attn_kernel<4><<<512, 256, 0, stream>>>(qT, kT, vM, Pb, Lbuf);
    merge_kernel<4><<<1024, 256, 0, stream>>>(Pb, Lbuf, gamma, attnP);
  }
  upsample_residual_kernel<<<8192, 256, 0, stream>>>(attnP, x, out);
}

// Round 15
// 83.088 us; speedup vs baseline: 2.2433x; 1.0940x over previous
//
#include <hip/hip_runtime.h>

// ---------------------------------------------------------------------------
// PAM module: [prep weights] -> fused conv3x3s2+qkv (bf16 MFMA implicit GEMM)
// -> flash attention v12 (64q/wave in 2 nt-phases, key-split x8 (x4 fallback),
// 2-buffer single-barrier pipeline, K-swizzled LDS, LDS P-transpose PV,
// static softmax, bf16 partials; LDS 43KB -> 3 blocks/CU)
// -> fused coalesced merge + bilinear upsample + residual.
// Shapes: x[8][64][128][128] f32, pooled h=w=64 -> N=4096, d_qk=32, d_v=64.
// ---------------------------------------------------------------------------

typedef __attribute__((ext_vector_type(8))) short bf16x8;   // 8 bf16 (4 VGPRs)
typedef __attribute__((ext_vector_type(4))) float f32x4;

#define DEV static __device__ __forceinline__

DEV unsigned f2bf(float f) {                  // RNE f32 -> bf16 bits
  union { float f; unsigned u; } a; a.f = f;
  return (a.u + 0x7FFFu + ((a.u >> 16) & 1u)) >> 16;
}
DEV float u2f(unsigned u) { union { unsigned u; float f; } a; a.u = u; return a.f; }
DEV unsigned cvtpk(float lo, float hi) {      // v_cvt_pk_bf16_f32 (RNE, 1 instr)
  unsigned r;
  asm("v_cvt_pk_bf16_f32 %0, %1, %2" : "=v"(r) : "v"(lo), "v"(hi));
  return r;
}
DEV bf16x8 mk_bf16x8(unsigned w0, unsigned w1, unsigned w2, unsigned w3) {
  union { unsigned u[4]; bf16x8 v; } x;
  x.u[0] = w0; x.u[1] = w1; x.u[2] = w2; x.u[3] = w3;
  return x.v;
}
DEV void gload_lds16(const void* g, void* l) {
  __builtin_amdgcn_global_load_lds(
      (const __attribute__((address_space(1))) void*)g,
      (__attribute__((address_space(3))) void*)l, 16, 0, 0);
}

// ---------------------------------------------------------------------------
// Kernel 0: weight prep.  Ag[oc][k=tap*64+ic] bf16 (conv A-operand, K=576);
// A2g[row][ic] bf16 (rows 0-31 q_w*log2e, 32-63 k_w, 64-127 v_w); bias2[128].
// ---------------------------------------------------------------------------
__global__ __launch_bounds__(256) void prep_kernel(
    const float* __restrict__ pw, const float* __restrict__ qw,
    const float* __restrict__ kw, const float* __restrict__ vw,
    const float* __restrict__ qb, const float* __restrict__ kb,
    const float* __restrict__ vb,
    unsigned short* __restrict__ Ag, unsigned short* __restrict__ A2g,
    float* __restrict__ bias2) {
  const float LOG2E = 1.4426950408889634f;
  const int i = blockIdx.x * 256 + threadIdx.x;
  if (i < 36864) {
    const int oc = i / 576, k = i - oc * 576;
    const int tap = k >> 6, ic = k & 63;
    Ag[i] = (unsigned short)f2bf(pw[(oc * 64 + ic) * 9 + tap]);
  }
  const int j = i - 36864;
  if (j >= 0 && j < 8192) {
    const int r = j >> 6, c = j & 63;
    if (r < 32)       A2g[j] = (unsigned short)f2bf(qw[r * 64 + c] * LOG2E);
    else if (r < 64)  A2g[j] = (unsigned short)f2bf(kw[(r - 32) * 64 + c]);
    else              A2g[j] = (unsigned short)f2bf(vw[(r - 64) * 64 + c]);
  }
  if (j >= 8192 && j < 8320) {
    const int r = j - 8192;
    bias2[r] = r < 32 ? qb[r] * LOG2E : (r < 64 ? kb[r - 32] : vb[r - 64]);
  }
}

// ---------------------------------------------------------------------------
// Kernel 1: fused conv3x3s2 + qkv, bf16 MFMA 16x16x32 (round-2 verified).
// ---------------------------------------------------------------------------
__global__ __launch_bounds__(256) void convqkv_kernel(
    const float* __restrict__ x, const unsigned short* __restrict__ Ag,
    const float* __restrict__ pool_b, const unsigned short* __restrict__ A2g,
    const float* __restrict__ bias2,
    unsigned short* __restrict__ qT, unsigned short* __restrict__ kT,
    unsigned short* __restrict__ vM) {
  const int b = blockIdx.x >> 6, oy = blockIdx.x & 63;
  const int t = threadIdx.x, w = t >> 6, lane = t & 63;
  const int lr = lane & 15, lg = lane >> 4;
  __shared__ unsigned short sIn[390 * 64];   // 48.75 KB, swizzled bytes
  __shared__ unsigned short sXP[64 * 64];    // 8 KB, swizzled bytes
  char* sInB = (char*)sIn;
  char* sXPB = (char*)sXP;

  bf16x8 af[18];
  {
    const unsigned short* ap = Ag + (w * 16 + lr) * 576 + (lg << 3);
    #pragma unroll
    for (int kc = 0; kc < 18; ++kc)
      af[kc] = *(const bf16x8*)(ap + kc * 32);
  }

  #pragma unroll
  for (int rr = 0; rr < 2; ++rr) {
    const int pos = t + rr * 256;
    if (pos < 390) {
      const int ky = pos / 130, xi = pos - ky * 130;
      const int iy = 2 * oy + ky - 1, ix = xi - 1;
      const bool ok = (iy >= 0) & (iy < 128) & (ix >= 0) & (ix < 128);
      const float* xs = x + ((size_t)(b * 64) * 128 + (ok ? iy : 0)) * 128 +
                        (ok ? ix : 0);
      const int sw = pos & 7;
      #pragma unroll
      for (int o = 0; o < 8; ++o) {
        float f[8];
        #pragma unroll
        for (int jj = 0; jj < 8; ++jj)
          f[jj] = ok ? xs[(size_t)(o * 8 + jj) * 16384] : 0.f;
        bf16x8 v = mk_bf16x8(cvtpk(f[0], f[1]), cvtpk(f[2], f[3]),
                             cvtpk(f[4], f[5]), cvtpk(f[6], f[7]));
        *(bf16x8*)(sInB + pos * 128 + ((o ^ sw) << 4)) = v;
      }
    }
  }
  __syncthreads();

  f32x4 acc[4];
  #pragma unroll
  for (int nt = 0; nt < 4; ++nt) acc[nt] = (f32x4){0.f, 0.f, 0.f, 0.f};
  #pragma unroll
  for (int kc = 0; kc < 18; ++kc) {
    const int tap = kc >> 1, ky = tap / 3, kx = tap - ky * 3;
    const int o = ((kc & 1) << 2) + lg;
    #pragma unroll
    for (int nt = 0; nt < 4; ++nt) {
      const int xi = 2 * (nt * 16 + lr) + kx;
      const int pos = ky * 130 + xi;
      bf16x8 bfr = *(const bf16x8*)(sInB + pos * 128 + ((o ^ (pos & 7)) << 4));
      acc[nt] = __builtin_amdgcn_mfma_f32_16x16x32_bf16(af[kc], bfr, acc[nt],
                                                        0, 0, 0);
    }
  }

  const int ocBase = w * 16 + (lg << 2);
  float pb[4];
  #pragma unroll
  for (int r = 0; r < 4; ++r) pb[r] = pool_b[ocBase + r];
  const int ocOct = ocBase >> 3;
  const int withinB = (ocBase & 7) * 2;
  #pragma unroll
  for (int nt = 0; nt < 4; ++nt) {
    const int pos = nt * 16 + lr;
    const unsigned p01 = cvtpk(acc[nt][0] + pb[0], acc[nt][1] + pb[1]);
    const unsigned p23 = cvtpk(acc[nt][2] + pb[2], acc[nt][3] + pb[3]);
    char* base = sXPB + pos * 128 + ((ocOct ^ (pos & 7)) << 4) + withinB;
    *(unsigned*)(base) = p01;
    *(unsigned*)(base + 4) = p23;
  }
  __syncthreads();

  bf16x8 a2[2][2];
  #pragma unroll
  for (int mt = 0; mt < 2; ++mt)
    #pragma unroll
    for (int kc2 = 0; kc2 < 2; ++kc2)
      a2[mt][kc2] = *(const bf16x8*)(A2g + ((2 * w + mt) * 16 + lr) * 64 +
                                     kc2 * 32 + (lg << 3));
  f32x4 acc2[2][4];
  #pragma unroll
  for (int mt = 0; mt < 2; ++mt)
    #pragma unroll
    for (int nt = 0; nt < 4; ++nt) acc2[mt][nt] = (f32x4){0.f, 0.f, 0.f, 0.f};
  #pragma unroll
  for (int kc2 = 0; kc2 < 2; ++kc2) {
    const int o2 = (kc2 << 2) + lg;
    #pragma unroll
    for (int nt = 0; nt < 4; ++nt) {
      const int pos = nt * 16 + lr;
      bf16x8 bfr = *(const bf16x8*)(sXPB + pos * 128 + ((o2 ^ (pos & 7)) << 4));
      acc2[0][nt] = __builtin_amdgcn_mfma_f32_16x16x32_bf16(a2[0][kc2], bfr,
                                                            acc2[0][nt], 0, 0, 0);
      acc2[1][nt] = __builtin_amdgcn_mfma_f32_16x16x32_bf16(a2[1][kc2], bfr,
                                                            acc2[1][nt], 0, 0, 0);
    }
  }

  const int n0g = oy << 6;
  #pragma unroll
  for (int mt = 0; mt < 2; ++mt) {
    const int rowB = (2 * w + mt) * 16 + (lg << 2);
    float b2[4];
    #pragma unroll
    for (int r = 0; r < 4; ++r) b2[r] = bias2[rowB + r];
    if (rowB < 32) {
      #pragma unroll
      for (int nt = 0; nt < 4; ++nt) {
        const int n = n0g + nt * 16 + lr;
        unsigned* dst = (unsigned*)(qT + (((size_t)(b << 12) + n) << 5) + rowB);
        dst[0] = cvtpk(acc2[mt][nt][0] + b2[0], acc2[mt][nt][1] + b2[1]);
        dst[1] = cvtpk(acc2[mt][nt][2] + b2[2], acc2[mt][nt][3] + b2[3]);
      }
    } else if (rowB < 64) {
      #pragma unroll
      for (int nt = 0; nt < 4; ++nt) {
        const int n = n0g + nt * 16 + lr;
        unsigned* dst = (unsigned*)(kT + (((size_t)(b << 12) + n) << 5) + rowB - 32);
        dst[0] = cvtpk(acc2[mt][nt][0] + b2[0], acc2[mt][nt][1] + b2[1]);
        dst[1] = cvtpk(acc2[mt][nt][2] + b2[2], acc2[mt][nt][3] + b2[3]);
      }
    } else {
      const int cv = rowB - 64;
      #pragma unroll
      for (int nt = 0; nt < 4; ++nt) {
        const int n = n0g + nt * 16 + lr;
        #pragma unroll
        for (int r = 0; r < 4; ++r)
          vM[(((size_t)(b << 6) + cv + r) << 12) + n] =
              (unsigned short)f2bf(acc2[mt][nt][r] + b2[r]);
      }
    }
  }
}

// ---------------------------------------------------------------------------
// Kernel 2: flash attention v12.  Template NSPLIT in {4, 8}.
// Grid 128*NSPLIT = (b = blk&7, u = (blk>>3)&15 [256-q tile], s = blk>>7).
// Block: 4 waves, wave w owns 64 queries processed in 2 nt-phases of 32 q
// (halves the per-wave P buffer: LDS 61.4 -> 43.0 KB -> 3 blocks/CU).
// CH=64/NSPLIT chunks of 64 keys; 2 staging bufs, prefetch dist 1, one
// barrier/chunk (r14-verified scheme).  K-swizzle + V source-octet swizzle
// and P-transpose addressing byte-identical to r14 (verified).
// ---------------------------------------------------------------------------
template <int NSPLIT>
__global__ __launch_bounds__(256, 2) void attn_kernel(
    const unsigned short* __restrict__ qT, const unsigned short* __restrict__ kT,
    const unsigned short* __restrict__ vM,
    unsigned short* __restrict__ Pb, float* __restrict__ Lbuf) {
  constexpr int CH = 64 / NSPLIT;       // chunks per split
  __shared__ char lds[24576];           // 2 bufs x (K 4KB | V 8KB)
  __shared__ char Plds[4][4608];        // per-wave P: 32 rows x 144B
  const int t = threadIdx.x, w = t >> 6, lane = t & 63;
  const int lr = lane & 15, lg = lane >> 4;
  const int b = blockIdx.x & 7;
  const int u = (blockIdx.x >> 3) & 15;
  const int s = blockIdx.x >> 7;        // key split
  const int n0 = (u << 8) + (w << 6);   // wave's 64 queries
  const int kb0 = s * (CH << 6);
  char* Pw = Plds[w];

  bf16x8 bq[4];
  #pragma unroll
  for (int nt = 0; nt < 4; ++nt)
    bq[nt] = *(const bf16x8*)(
        qT + (((size_t)(b << 12) + n0 + nt * 16 + lr) << 5) + (lg << 3));

  const unsigned short* ksrc = kT + ((size_t)b << 17);    // [key][32]
  const unsigned short* vsrcb = vM + ((size_t)b << 18);   // [c][4096]

  f32x4 acc[4][4];
  #pragma unroll
  for (int nt = 0; nt < 4; ++nt)
    #pragma unroll
    for (int ct = 0; ct < 4; ++ct) acc[nt][ct] = (f32x4){0.f, 0.f, 0.f, 0.f};
  float l_run[4] = {0.f, 0.f, 0.f, 0.f};

  const int vsw = (lane & 7) ^ ((lane >> 3) & 7);   // V source octet swizzle
  const int klocal = (w << 4) + (lane >> 2);
  const int kseg = (lane & 3) ^ ((klocal >> 1) & 3); // source seg for slot

  #define STAGE(ci_) {                                                         \
    const int kb_ = kb0 + (((ci_) & (CH - 1)) << 6);                           \
    char* sb_ = lds + ((ci_) & 1) * 12288;                                     \
    gload_lds16((const void*)(ksrc + (((size_t)(kb_ + klocal)) << 5) +         \
                  (kseg << 3)),                                                \
                sb_ + (w << 10));                                              \
    gload_lds16((const void*)(vsrcb +                                          \
                  (((size_t)((w << 4) + (lane >> 3))) << 12) + kb_ +           \
                  (vsw << 3)),                                                 \
                sb_ + 4096 + (w << 11));                                       \
    gload_lds16((const void*)(vsrcb +                                          \
                  (((size_t)((w << 4) + 8 + (lane >> 3))) << 12) + kb_ +       \
                  (vsw << 3)),                                                 \
                sb_ + 4096 + (w << 11) + 1024);                                \
  }

  STAGE(0);

  for (int cc = 0; cc < CH; ++cc) {
    asm volatile("s_waitcnt vmcnt(0)" ::: "memory");   // chunk cc landed
    __builtin_amdgcn_s_barrier();        // all waves consumed buf (cc-1)&1
    __builtin_amdgcn_sched_barrier(0);
    if (cc + 1 < CH) STAGE(cc + 1);      // overwrites buf (cc-1)&1: safe
    char* base = lds + (cc & 1) * 12288;

    #pragma unroll
    for (int p = 0; p < 2; ++p) {
      // ---- QK^T for queries 2p, 2p+1 (32 q)
      f32x4 st[2][4];
      const f32x4 z4 = {0.f, 0.f, 0.f, 0.f};
      __builtin_amdgcn_s_setprio(1);
      #pragma unroll
      for (int j = 0; j < 4; ++j) {
        const int key = 16 * j + lr;
        const bf16x8 ka = *(const bf16x8*)(
            base + (key << 6) + ((lg ^ ((key >> 1) & 3)) << 4));
        st[0][j] = __builtin_amdgcn_mfma_f32_16x16x32_bf16(ka, bq[2 * p], z4,
                                                           0, 0, 0);
        st[1][j] = __builtin_amdgcn_mfma_f32_16x16x32_bf16(ka, bq[2 * p + 1],
                                                           z4, 0, 0, 0);
      }
      __builtin_amdgcn_s_setprio(0);

      // ---- static softmax numerator P = 2^s; transpose into LDS (32 rows)
      #pragma unroll
      for (int q = 0; q < 2; ++q) {
        float ps0 = 0.f, ps1 = 0.f;
        #pragma unroll
        for (int j = 0; j < 4; ++j) {
          const float p0 = __builtin_amdgcn_exp2f(st[q][j][0]);
          const float p1 = __builtin_amdgcn_exp2f(st[q][j][1]);
          const float p2 = __builtin_amdgcn_exp2f(st[q][j][2]);
          const float p3 = __builtin_amdgcn_exp2f(st[q][j][3]);
          ps0 += p0 + p1;
          ps1 += p2 + p3;
          *(uint2*)(Pw + (q * 16 + lr) * 144 + (((j << 2) + lg) << 3)) =
              (uint2){cvtpk(p0, p1), cvtpk(p2, p3)};
        }
        l_run[2 * p + q] += ps0 + ps1;
      }

      // ---- PV for this phase
      #pragma unroll
      for (int h = 0; h < 2; ++h) {
        bf16x8 vr[4];
        #pragma unroll
        for (int ct = 0; ct < 4; ++ct) {
          const int c = (ct << 4) + lr;
          const int o = (h << 2) + lg;
          vr[ct] = *(const bf16x8*)(base + 4096 + (c << 7) +
                                    ((o ^ (lr & 7)) << 4));
        }
        #pragma unroll
        for (int q = 0; q < 2; ++q) {
          const bf16x8 pbf = *(const bf16x8*)(
              Pw + (q * 16 + lr) * 144 + (((h << 3) + (lg << 1)) << 3));
          __builtin_amdgcn_s_setprio(1);
          #pragma unroll
          for (int ct = 0; ct < 4; ++ct)
            acc[2 * p + q][ct] = __builtin_amdgcn_mfma_f32_16x16x32_bf16(
                vr[ct], pbf, acc[2 * p + q][ct], 0, 0, 0);
          __builtin_amdgcn_s_setprio(0);
        }
      }
    }
  }

  #pragma unroll
  for (int nt = 0; nt < 4; ++nt) {
    l_run[nt] += __shfl_xor(l_run[nt], 16, 64);
    l_run[nt] += __shfl_xor(l_run[nt], 32, 64);
  }

  unsigned short* dst = Pb + ((size_t)s << 21);
  #pragma unroll
  for (int nt = 0; nt < 4; ++nt) {
    const int q = n0 + nt * 16 + lr;
    #pragma unroll
    for (int ct = 0; ct < 4; ++ct)
      #pragma unroll
      for (int r = 0; r < 4; ++r) {
        const int c = (ct << 4) + (lg << 2) + r;
        dst[((size_t)((b << 6) + c) << 12) + q] =
            (unsigned short)f2bf(acc[nt][ct][r]);
      }
  }
  if (lane < 16) {
    #pragma unroll
    for (int nt = 0; nt < 4; ++nt)
      Lbuf[((size_t)(s * 8 + b) << 12) + n0 + nt * 16 + lane] = l_run[nt];
  }
  #undef STAGE
}

// ---------------------------------------------------------------------------
// Kernel 3: fused coalesced merge + bilinear upsample + residual.
// One block per (b,c) plane (512 blocks).  Phase 1: merge splits into a
// 4096-f32 LDS plane (uint4 bf16x8 loads, fully coalesced; this is the
// round-11-verified merge math writing to LDS).  Phase 2: upsample 64->128
// (align_corners) reading the plane from LDS + residual add.
// ---------------------------------------------------------------------------
template <int NSPLIT>
__global__ __launch_bounds__(256) void merge_upsample_kernel(
    const unsigned short* __restrict__ Pb, const float* __restrict__ Lbuf,
    const float* __restrict__ gamma_p, const float* __restrict__ x,
    float* __restrict__ out) {
  __shared__ float sA[4096];            // merged attn plane (64x64)
  const int t = threadIdx.x;
  const int b = blockIdx.x >> 6, c = blockIdx.x & 63;
  const float g = gamma_p[0];
  const size_t basebc = ((size_t)((b << 6) + c) << 12);

  #pragma unroll
  for (int i = 0; i < 2; ++i) {
    const int n0 = (t + (i << 8)) << 3;
    float num[8] = {0.f, 0.f, 0.f, 0.f, 0.f, 0.f, 0.f, 0.f};
    #pragma unroll
    for (int s = 0; s < NSPLIT; ++s) {
      const uint4 v = *(const uint4*)(Pb + ((size_t)s << 21) + basebc + n0);
      num[0] += u2f(v.x << 16); num[1] += u2f(v.x & 0xffff0000u);
      num[2] += u2f(v.y << 16); num[3] += u2f(v.y & 0xffff0000u);
      num[4] += u2f(v.z << 16); num[5] += u2f(v.z & 0xffff0000u);
      num[6] += u2f(v.w << 16); num[7] += u2f(v.w & 0xffff0000u);
    }
    float den[8] = {0.f, 0.f, 0.f, 0.f, 0.f, 0.f, 0.f, 0.f};
    #pragma unroll
    for (int s = 0; s < NSPLIT; ++s) {
      const float* lp = Lbuf + (((size_t)(s * 8 + b)) << 12) + n0;
      const f32x4 l0 = *(const f32x4*)lp;
      const f32x4 l1 = *(const f32x4*)(lp + 4);
      #pragma unroll
      for (int j = 0; j < 4; ++j) { den[j] += l0[j]; den[4 + j] += l1[j]; }
    }
    #pragma unroll
    for (int j = 0; j < 8; ++j) sA[n0 + j] = g * num[j] / den[j];
  }
  __syncthreads();

  const float sr = 63.0f / 127.0f;
  const float* xb = x + (((size_t)((b << 6) + c)) << 14);
  float* ob = out + (((size_t)((b << 6) + c)) << 14);
  for (int k = 0; k < 16; ++k) {
    const int qid = t + (k << 8);       // 0..4095 output quads
    const int Y = qid >> 5, X0 = (qid & 31) << 2;
    const float fy = Y * sr;
    int iy = (int)fy; if (iy > 62) iy = 62;
    const float ty = fy - (float)iy;
    const float* r0 = sA + iy * 64;
    const float* r1 = r0 + 64;
    float tmp[4];
    #pragma unroll
    for (int kk = 0; kk < 4; ++kk) {
      const int X = X0 + kk;
      const float fx = X * sr;
      int ix = (int)fx; if (ix > 62) ix = 62;
      const float tx = fx - (float)ix;
      const float v0 = r0[ix] + tx * (r0[ix + 1] - r0[ix]);
      const float v1 = r1[ix] + tx * (r1[ix + 1] - r1[ix]);
      tmp[kk] = v0 + ty * (v1 - v0);
    }
    const size_t o = ((size_t)Y << 7) + X0;
    const f32x4 xv = *(const f32x4*)(xb + o);
    f32x4 ov = {tmp[0] + xv[0], tmp[1] + xv[1], tmp[2] + xv[2], tmp[3] + xv[3]};
    *(f32x4*)(ob + o) = ov;
  }
}

// ---------------------------------------------------------------------------
extern "C" void kernel_launch(void* const* d_in, const int* in_sizes, int n_in,
                              void* d_out, int out_size, void* d_ws, size_t ws_size,
                              hipStream_t stream) {
  const float* x      = (const float*)d_in[0];
  const float* pool_w = (const float*)d_in[1];
  const float* pool_b = (const float*)d_in[2];
  const float* q_w    = (const float*)d_in[3];
  const float* q_b    = (const float*)d_in[4];
  const float* k_w    = (const float*)d_in[5];
  const float* k_b    = (const float*)d_in[6];
  const float* v_w    = (const float*)d_in[7];
  const float* v_b    = (const float*)d_in[8];
  const float* gamma  = (const float*)d_in[9];
  float* out = (float*)d_out;

  char* ws = (char*)d_ws;
  unsigned short* Ag   = (unsigned short*)(ws);             // 73,728 B
  unsigned short* A2g  = (unsigned short*)(ws + 81920);     // 16,384 B
  float* bias2         = (float*)(ws + 98304);              // 512 B
  unsigned short* qT   = (unsigned short*)(ws + 1048576);   // 2 MiB
  unsigned short* kT   = (unsigned short*)(ws + 3145728);   // 2 MiB
  unsigned short* vM   = (unsigned short*)(ws + 5242880);   // 4 MiB
  unsigned short* Pb   = (unsigned short*)(ws + 9437184);   // NSPLIT x 4 MiB

  prep_kernel<<<177, 256, 0, stream>>>(pool_w, q_w, k_w, v_w, q_b, k_b, v_b,
                                       Ag, A2g, bias2);
  convqkv_kernel<<<512, 256, 0, stream>>>(x, Ag, pool_b, A2g, bias2, qT, kT, vM);

  // 8-split needs 9437184 + 8*4194304 + 8*131072 = 44,040,192 B of ws.
  if (ws_size >= 44040192u) {
    float* Lbuf = (float*)(ws + 9437184 + 8 * 4194304);
    attn_kernel<8><<<1024, 256, 0, stream>>>(qT, kT, vM, Pb, Lbuf);
    merge_upsample_kernel<8><<<512, 256, 0, stream>>>(Pb, Lbuf, gamma, x, out);
  } else {
    float* Lbuf = (float*)(ws + 9437184 + 4 * 4194304);
    attn_kernel<4><<<512, 256, 0, stream>>>(qT, kT, vM, Pb, Lbuf);
    merge_upsample_kernel<4><<<512, 256, 0, stream>>>(Pb, Lbuf, gamma, x, out);
  }
}